// Round 14
// baseline (2720.544 us; speedup 1.0000x reference)
//
#include <hip/hip_runtime.h>
#include <hip/hip_bf16.h>

// HGT forward, MI355X — ROUND 14: bf16-packed k/v gather tables (half gather bytes)
// + 128x64-tile GEMM (8x4 microtile, 2x FMA/LDS ratio) + no-memset agg first-write.
// CSR-gather attention, folded arel, post-agg mrel. f32 outputs.
// ws ~128 MB (<153.6 proven). d_out scratch: agg1 in emb region, CSR+qWA in rec.

#define HH 8
#define HID 128
#define INC 256
#define TTYPES 2

typedef unsigned short u16;
typedef unsigned int u32;

__device__ __forceinline__ float lo2f(u32 u) { return __uint_as_float(u << 16); }
__device__ __forceinline__ float hi2f(u32 u) { return __uint_as_float(u & 0xffff0000u); }
__device__ __forceinline__ u16 f2bf(float f) {
    u32 i = __float_as_uint(f);
    u32 r = i + 0x7fffu + ((i >> 16) & 1u);   // RNE
    return (u16)(r >> 16);
}
__device__ __forceinline__ float gelu_f(float x) {
    return 0.5f * x * (1.0f + erff(x * 0.7071067811865476f));
}

// ---------------- Tiled GEMM: 128x64 block tile, 8x4 per-thread microtile -----------
// out[n,j] = act(sum_c act_in(in[n,c])*W[c,j] + b[j])
// AIN: 0 none, 1 gelu. AOUT: 0 none, 1 relu, 2 skip blend out = g*v + (1-g)*out_old.
// TOUT: float (plain f32) or u16 (bf16 store, AOUT must be 0).
template <int CIN, int COUT, int AIN, int AOUT, typename TOUT>
__global__ __launch_bounds__(256) void gemm_kernel(
    const float* __restrict__ in, const float* __restrict__ W,
    const float* __restrict__ bias, TOUT* __restrict__ out, int nrows,
    const float* __restrict__ gatep)
{
    __shared__ __align__(16) float Wl[64 * 64];     // K-chunk of W [64][64]
    __shared__ __align__(16) float Rt[64 * 132];    // transposed rows [c][128]+pad
    const int tid = threadIdx.x;
    const int rowbase = blockIdx.x * 128;
    const int colbase = blockIdx.y * 64;

    const int tcol = tid & 15;
    const int trow = tid >> 4;
    const int col0 = tcol * 4;
    const int row0 = trow * 8;
    float acc[8][4] = {};

    for (int kc = 0; kc < CIN; kc += 64) {
        __syncthreads();
        for (int i = tid; i < 64 * 16; i += 256) {     // W chunk
            int r = i >> 4, j4 = i & 15;
            ((float4*)Wl)[r * 16 + j4] =
                *(const float4*)&W[(size_t)(kc + r) * COUT + colbase + j4 * 4];
        }
        for (int i = tid; i < 128 * 16; i += 256) {    // rows, transposed
            int r = i >> 4, c4 = i & 15;
            int gr = rowbase + r;
            float4 v4 = make_float4(0.f, 0.f, 0.f, 0.f);
            if (gr < nrows) v4 = *(const float4*)&in[(size_t)gr * CIN + kc + c4 * 4];
            if (AIN == 1) {
                v4.x = gelu_f(v4.x); v4.y = gelu_f(v4.y);
                v4.z = gelu_f(v4.z); v4.w = gelu_f(v4.w);
            }
            int cc = c4 * 4;
            Rt[(cc + 0) * 132 + r] = v4.x;
            Rt[(cc + 1) * 132 + r] = v4.y;
            Rt[(cc + 2) * 132 + r] = v4.z;
            Rt[(cc + 3) * 132 + r] = v4.w;
        }
        __syncthreads();
#pragma unroll 4
        for (int c = 0; c < 64; ++c) {
            const float4 ra = *(const float4*)&Rt[c * 132 + row0];
            const float4 rb = *(const float4*)&Rt[c * 132 + row0 + 4];
            const float4 wv = *(const float4*)&Wl[c * 64 + col0];
            acc[0][0] += ra.x * wv.x; acc[0][1] += ra.x * wv.y;
            acc[0][2] += ra.x * wv.z; acc[0][3] += ra.x * wv.w;
            acc[1][0] += ra.y * wv.x; acc[1][1] += ra.y * wv.y;
            acc[1][2] += ra.y * wv.z; acc[1][3] += ra.y * wv.w;
            acc[2][0] += ra.z * wv.x; acc[2][1] += ra.z * wv.y;
            acc[2][2] += ra.z * wv.z; acc[2][3] += ra.z * wv.w;
            acc[3][0] += ra.w * wv.x; acc[3][1] += ra.w * wv.y;
            acc[3][2] += ra.w * wv.z; acc[3][3] += ra.w * wv.w;
            acc[4][0] += rb.x * wv.x; acc[4][1] += rb.x * wv.y;
            acc[4][2] += rb.x * wv.z; acc[4][3] += rb.x * wv.w;
            acc[5][0] += rb.y * wv.x; acc[5][1] += rb.y * wv.y;
            acc[5][2] += rb.y * wv.z; acc[5][3] += rb.y * wv.w;
            acc[6][0] += rb.z * wv.x; acc[6][1] += rb.z * wv.y;
            acc[6][2] += rb.z * wv.z; acc[6][3] += rb.z * wv.w;
            acc[7][0] += rb.w * wv.x; acc[7][1] += rb.w * wv.y;
            acc[7][2] += rb.w * wv.z; acc[7][3] += rb.w * wv.w;
        }
    }

    float bv[4];
#pragma unroll
    for (int j = 0; j < 4; ++j) bv[j] = bias[colbase + col0 + j];
    float g = 0.f;
    if (AOUT == 2) g = 1.0f / (1.0f + expf(-gatep[0]));
#pragma unroll
    for (int r = 0; r < 8; ++r) {
        int gr = rowbase + row0 + r;
        if (gr >= nrows) continue;
        size_t base = (size_t)gr * COUT + colbase + col0;
#pragma unroll
        for (int j = 0; j < 4; ++j) {
            float v = acc[r][j] + bv[j];
            if (AOUT == 1) v = fmaxf(v, 0.f);
            if constexpr (sizeof(TOUT) == 2) {
                ((u16*)out)[base + j] = f2bf(v);
            } else {
                float* of = (float*)out;
                if (AOUT == 2) v = g * v + (1.0f - g) * of[base + j];
                of[base + j] = v;
            }
        }
    }
}

// ------- fuse arel into qW: qWA[c, h*16+d] = sum_e qW[c, h*16+e]*arel[h,d,e] --------
__global__ __launch_bounds__(256) void fuse_kernel(
    const float* __restrict__ qW, const float* __restrict__ qb,
    const float* __restrict__ arel, float* __restrict__ qWA, float* __restrict__ qbA)
{
    __shared__ float Al[2048];
    int tid = threadIdx.x;
    for (int i = tid; i < 2048; i += 256) Al[i] = arel[i];
    __syncthreads();
    int idx = blockIdx.x * 256 + tid;      // 64 blocks * 256 = 16384 entries
    int c = idx >> 7, col = idx & 127;
    int h = col >> 4, d = col & 15;
    const float* Ah = &Al[h * 256 + d * 16];
    const float* qr = &qW[(size_t)c * 128 + h * 16];
    float acc = 0.f;
#pragma unroll
    for (int e = 0; e < 16; ++e) acc += qr[e] * Ah[e];
    qWA[idx] = acc;
    if (blockIdx.x == 0 && tid < 128) {
        int h2 = tid >> 4, d2 = tid & 15;
        const float* Ah2 = &Al[h2 * 256 + d2 * 16];
        const float* qb2 = &qb[h2 * 16];
        float accb = 0.f;
#pragma unroll
        for (int e = 0; e < 16; ++e) accb += qb2[e] * Ah2[e];
        qbA[tid] = accb;
    }
}

// ---------------- CSR-gather attention: one wave per destination node ----------------
// k/v stored as packed bf16 pairs (u32 per lane). 1-deep prefetch of next edge rows.
__global__ __launch_bounds__(256) void gather_kernel(
    const float* __restrict__ qq, const u32* __restrict__ kb,
    const u32* __restrict__ vb, const int* __restrict__ off,
    const int* __restrict__ csrc, const float* __restrict__ prel,
    const float* __restrict__ mrel, float* __restrict__ agg, int N, int accum)
{
    __shared__ float M[2048];   // mrel [h][d][e]
    int tid = threadIdx.x;
    for (int i = tid; i < 2048; i += 256) M[i] = mrel[i];
    __syncthreads();
    int lane = tid & 63, wid = tid >> 6;
    int h = lane >> 3, dp = lane & 7;
    int dst = blockIdx.x * 4 + wid;
    if (dst >= N) return;

    float prl = prel[h] * 0.25f;   // * 1/sqrt(D)
    const float2 qv = *(const float2*)&qq[(size_t)dst * 128 + lane * 2];
    int beg = off[dst], end = off[dst + 1];
    float acc0 = 0.f, acc1 = 0.f, ssum = 0.f;

    u32 kA = 0, vA = 0;
    if (beg < end) {
        int s0 = csrc[beg];
        kA = kb[(size_t)s0 * 64 + lane];
        vA = vb[(size_t)s0 * 64 + lane];
    }
    for (int e = beg; e < end; ++e) {
        u32 kB = 0, vB = 0;
        if (e + 1 < end) {          // prefetch next edge's rows
            int s1 = csrc[e + 1];
            kB = kb[(size_t)s1 * 64 + lane];
            vB = vb[(size_t)s1 * 64 + lane];
        }
        float p = qv.x * lo2f(kA) + qv.y * hi2f(kA);
        p += __shfl_xor(p, 1);
        p += __shfl_xor(p, 2);
        p += __shfl_xor(p, 4);      // 8-lane head reduction
        float sarg = fminf(fmaxf(p * prl, -60.f), 60.f);
        float ex = expf(sarg);
        ssum += ex;
        acc0 += ex * lo2f(vA);
        acc1 += ex * hi2f(vA);
        kA = kB; vA = vB;
    }
    float inv = 1.0f / (ssum + 1e-16f);
    acc0 *= inv; acc1 *= inv;

    // post-aggregation mrel: out[h][e] = sum_d t[h][d]*M[h][d][e]
    float o0 = 0.f, o1 = 0.f;
    const float* Mh = &M[h * 256];
#pragma unroll
    for (int dd = 0; dd < 8; ++dd) {
        float b0 = __shfl(acc0, (h << 3) | dd);   // t[h][2dd]
        float b1 = __shfl(acc1, (h << 3) | dd);   // t[h][2dd+1]
        const float2 m0 = *(const float2*)&Mh[(2 * dd) * 16 + dp * 2];
        const float2 m1 = *(const float2*)&Mh[(2 * dd + 1) * 16 + dp * 2];
        o0 += b0 * m0.x + b1 * m1.x;
        o1 += b0 * m0.y + b1 * m1.y;
    }
    float* ap = &agg[(size_t)dst * 128 + lane * 2];
    if (accum) { ap[0] += o0; ap[1] += o1; }
    else       { ap[0] = o0;  ap[1] = o1;  }
}

// ---------------- CSR build --------------------------------------------------------
__global__ void hist_kernel(const int* __restrict__ dst, int* __restrict__ deg, int E) {
    int i = blockIdx.x * 256 + threadIdx.x;
    if (i < E) atomicAdd(&deg[dst[i]], 1);
}
__global__ __launch_bounds__(1024) void scan_kernel(
    const int* __restrict__ deg, int* __restrict__ off, int N)
{
    __shared__ int s[1024];
    int tid = threadIdx.x;
    int C = (N + 1023) >> 10;
    int b = tid * C;
    int sum = 0;
    for (int i = 0; i < C; ++i) { int idx = b + i; if (idx < N) sum += deg[idx]; }
    s[tid] = sum;
    __syncthreads();
    for (int d = 1; d < 1024; d <<= 1) {
        int t = (tid >= d) ? s[tid - d] : 0;
        __syncthreads();
        s[tid] += t;
        __syncthreads();
    }
    int run = s[tid] - sum;   // exclusive prefix of this chunk
    for (int i = 0; i < C; ++i) {
        int idx = b + i;
        if (idx < N) { off[idx] = run; run += deg[idx]; }
    }
    if (tid == 1023) off[N] = s[1023];
}
__global__ void scatter_kernel(const int* __restrict__ src, const int* __restrict__ dst,
                               const int* __restrict__ off, int* __restrict__ cnt,
                               int* __restrict__ csrc, int E)
{
    int i = blockIdx.x * 256 + threadIdx.x;
    if (i < E) {
        int d = dst[i];
        int pos = off[d] + atomicAdd(&cnt[d], 1);
        csrc[pos] = src[i];
    }
}

// ---------------- L2 normalize: one wave per row, f32 -> f32 ------------------------
__global__ __launch_bounds__(256) void nnorm(
    const float* __restrict__ h0, float* __restrict__ emb, int N)
{
    int lane = threadIdx.x & 63, wid = threadIdx.x >> 6;
    int n = blockIdx.x * 4 + wid;
    if (n >= N) return;
    const float2 v = *(const float2*)&h0[(size_t)n * 128 + lane * 2];
    float s = v.x * v.x + v.y * v.y;
#pragma unroll
    for (int m = 1; m < 64; m <<= 1) s += __shfl_xor(s, m);
    float sc = 1.0f / fmaxf(sqrtf(s), 1e-12f);
    if (!isfinite(sc)) sc = 0.f;
    float2* op = (float2*)&emb[(size_t)n * 128 + lane * 2];
    *op = make_float2(v.x * sc, v.y * sc);
}

// ---------------- sentinel (f32) ----------------------------------------------------
__global__ void sentinel_kernel(float* out, int n, float val) {
    int i = blockIdx.x * 256 + threadIdx.x;
    if (i < n) out[i] = val;
}

extern "C" void kernel_launch(void* const* d_in, const int* in_sizes, int n_in,
                              void* d_out, int out_size, void* d_ws, size_t ws_size,
                              hipStream_t stream)
{
    const int N = in_sizes[0] / (TTYPES * INC);
    const int E = in_sizes[19] / 2;
    const size_t NH = (size_t)N * HID;

    // ws need: hbuf 2NH f32 + qqb NH f32 + agg0 NH f32 + kbuf/vbuf N*64 u32 each
    const size_t need = 4 * NH * 4 + 2 * NH * 2;   // ~128 MB
    if (ws_size < need) {
        sentinel_kernel<<<(out_size + 255) / 256, 256, 0, stream>>>(
            (float*)d_out, out_size, 30.0f);
        return;
    }

    const float* x     = (const float*)d_in[0];
    const float* encW  = (const float*)d_in[1];
    const float* encb  = (const float*)d_in[2];
    const float* kW    = (const float*)d_in[3];
    const float* kb_   = (const float*)d_in[4];
    const float* qW    = (const float*)d_in[5];
    const float* qb    = (const float*)d_in[6];
    const float* vW    = (const float*)d_in[7];
    const float* vb_   = (const float*)d_in[8];
    const float* aW    = (const float*)d_in[9];
    const float* ab    = (const float*)d_in[10];
    const float* skipw = (const float*)d_in[11];
    const float* arel  = (const float*)d_in[12];
    const float* mrel  = (const float*)d_in[13];
    const float* prel  = (const float*)d_in[14];
    const float* dW1   = (const float*)d_in[15];
    const float* db1   = (const float*)d_in[16];
    const float* dW2   = (const float*)d_in[17];
    const float* db2   = (const float*)d_in[18];

    // ---- ws layout: hbuf[2NH] f32 | qqb NH f32 | agg0 NH f32 | kbuf | vbuf (u32) ----
    float* hbuf = (float*)d_ws;
    float* qqb  = hbuf + 2 * NH;
    float* agg0 = qqb + NH;
    u32* kbuf   = (u32*)(agg0 + NH);     // [N][64] packed bf16 pairs
    u32* vbuf   = kbuf + (size_t)N * 64;

    // ---- d_out scratch ----
    float* agg1 = (float*)d_out;                 // emb region, dead before nnorm
    int*   ip   = (int*)((float*)d_out + NH);    // rec region
    int* deg = ip;            ip += N;
    int* cnt = ip;            ip += N;
    int* offs[4];  for (int e = 0; e < 4; ++e) { offs[e] = ip; ip += N + 1; }
    int* csrcs[4]; for (int e = 0; e < 4; ++e) { csrcs[e] = ip; ip += E; }
    float* qWA = (float*)ip;
    float* qbA = qWA + HID * HID;

    static const int st_[4] = {0, 1, 0, 1};
    static const int dt_[4] = {1, 0, 0, 1};
    float* aggs[2] = {agg0, agg1};

    const int egrid = (E + 255) / 256;
    const int RT    = (N + 127) / 128;
    const int GW    = (N + 3) / 4;

    // ---- CSR build (once, reused by both layers) ----
    for (int et = 0; et < 4; ++et) {
        const int* ei = (const int*)d_in[19 + et];
        hipMemsetAsync(deg, 0, (size_t)N * 4, stream);
        hist_kernel<<<egrid, 256, 0, stream>>>(ei + E, deg, E);
        scan_kernel<<<1, 1024, 0, stream>>>(deg, offs[et], N);
        hipMemsetAsync(cnt, 0, (size_t)N * 4, stream);
        scatter_kernel<<<egrid, 256, 0, stream>>>(ei, ei + E, offs[et], cnt,
                                                  csrcs[et], E);
    }

    // ---- encoder: h[t] = relu(x[t] @ encW[t] + encb[t]) ----
    for (int t = 0; t < TTYPES; ++t) {
        gemm_kernel<INC, HID, 0, 1, float><<<dim3(RT, 2), 256, 0, stream>>>(
            x + (size_t)t * N * INC, encW + (size_t)t * INC * HID, encb + t * HID,
            hbuf + t * NH, N, nullptr);
    }

    for (int l = 0; l < 2; ++l) {
        // group by SOURCE type: k/v computed once per st; all reads pre-update.
        // st==0 gathers write agg (accum=0), st==1 gathers accumulate.
        for (int st = 0; st < TTYPES; ++st) {
            int bs = l * 2 + st;
            gemm_kernel<HID, HID, 0, 0, u16><<<dim3(RT, 2), 256, 0, stream>>>(
                hbuf + st * NH, kW + (size_t)bs * HID * HID, kb_ + (size_t)bs * HID,
                (u16*)kbuf, N, nullptr);
            gemm_kernel<HID, HID, 0, 0, u16><<<dim3(RT, 2), 256, 0, stream>>>(
                hbuf + st * NH, vW + (size_t)bs * HID * HID, vb_ + (size_t)bs * HID,
                (u16*)vbuf, N, nullptr);
            for (int et = 0; et < 4; ++et) {
                if (st_[et] != st) continue;
                int dt = dt_[et];
                int rel = l * 4 + et;
                int bd  = l * 2 + dt;
                fuse_kernel<<<64, 256, 0, stream>>>(
                    qW + (size_t)bd * HID * HID, qb + (size_t)bd * HID,
                    arel + (size_t)rel * 2048, qWA, qbA);
                gemm_kernel<HID, HID, 0, 0, float><<<dim3(RT, 2), 256, 0, stream>>>(
                    hbuf + dt * NH, qWA, qbA, qqb, N, nullptr);
                gather_kernel<<<GW, 256, 0, stream>>>(
                    qqb, kbuf, vbuf, offs[et], csrcs[et],
                    prel + (size_t)rel * HH, mrel + (size_t)rel * 2048,
                    aggs[dt], N, st);
            }
        }
        // h[t] = g*(gelu(agg[t]) @ aW + ab) + (1-g)*h[t]
        for (int t = 0; t < TTYPES; ++t) {
            int b = l * 2 + t;
            gemm_kernel<HID, HID, 1, 2, float><<<dim3(RT, 2), 256, 0, stream>>>(
                aggs[t], aW + (size_t)b * HID * HID, ab + (size_t)b * HID,
                hbuf + t * NH, N, skipw + b);
        }
    }

    float* emb = (float*)d_out;           // [N][128] f32
    float* rec = emb + NH;                // [N][256] f32
    nnorm<<<GW, 256, 0, stream>>>(hbuf, emb, N);
    gemm_kernel<HID, HID, 0, 1, float><<<dim3(RT, 2), 256, 0, stream>>>(
        hbuf, dW1, db1, agg0, N, nullptr);
    gemm_kernel<HID, INC, 0, 0, float><<<dim3(RT, 4), 256, 0, stream>>>(
        agg0, dW2, db2, rec, N, nullptr);
}

// Round 15
// 2512.441 us; speedup vs baseline: 1.0828x; 1.0828x over previous
//
#include <hip/hip_runtime.h>
#include <hip/hip_bf16.h>

// HGT forward, MI355X — ROUND 15: 4-deep prefetch pipeline in gather (latency fix)
// + interleaved kv table ([N][128] u32: k lanes 0-63, v lanes 64-127).
// CSR-gather attention, folded arel, post-agg mrel, f32 outputs.
// ws ~128 MB. d_out scratch: agg1 in emb region, CSR+qWA in rec region.

#define HH 8
#define HID 128
#define INC 256
#define TTYPES 2

typedef unsigned short u16;
typedef unsigned int u32;

__device__ __forceinline__ float lo2f(u32 u) { return __uint_as_float(u << 16); }
__device__ __forceinline__ float hi2f(u32 u) { return __uint_as_float(u & 0xffff0000u); }
__device__ __forceinline__ u16 f2bf(float f) {
    u32 i = __float_as_uint(f);
    u32 r = i + 0x7fffu + ((i >> 16) & 1u);   // RNE
    return (u16)(r >> 16);
}
__device__ __forceinline__ float gelu_f(float x) {
    return 0.5f * x * (1.0f + erff(x * 0.7071067811865476f));
}

// ---------------- Tiled GEMM: 128x64 block tile, 8x4 per-thread microtile -----------
// out[n,j] = act(sum_c act_in(in[n,c])*W[c,j] + b[j]);  row stride ldout (TOUT elems).
// AIN: 0 none, 1 gelu. AOUT: 0 none, 1 relu, 2 skip blend out = g*v + (1-g)*out_old.
template <int CIN, int COUT, int AIN, int AOUT, typename TOUT>
__global__ __launch_bounds__(256) void gemm_kernel(
    const float* __restrict__ in, const float* __restrict__ W,
    const float* __restrict__ bias, TOUT* __restrict__ out, int nrows,
    const float* __restrict__ gatep, int ldout)
{
    __shared__ __align__(16) float Wl[64 * 64];     // K-chunk of W [64][64]
    __shared__ __align__(16) float Rt[64 * 132];    // transposed rows [c][128]+pad
    const int tid = threadIdx.x;
    const int rowbase = blockIdx.x * 128;
    const int colbase = blockIdx.y * 64;

    const int tcol = tid & 15;
    const int trow = tid >> 4;
    const int col0 = tcol * 4;
    const int row0 = trow * 8;
    float acc[8][4] = {};

    for (int kc = 0; kc < CIN; kc += 64) {
        __syncthreads();
        for (int i = tid; i < 64 * 16; i += 256) {     // W chunk
            int r = i >> 4, j4 = i & 15;
            ((float4*)Wl)[r * 16 + j4] =
                *(const float4*)&W[(size_t)(kc + r) * COUT + colbase + j4 * 4];
        }
        for (int i = tid; i < 128 * 16; i += 256) {    // rows, transposed
            int r = i >> 4, c4 = i & 15;
            int gr = rowbase + r;
            float4 v4 = make_float4(0.f, 0.f, 0.f, 0.f);
            if (gr < nrows) v4 = *(const float4*)&in[(size_t)gr * CIN + kc + c4 * 4];
            if (AIN == 1) {
                v4.x = gelu_f(v4.x); v4.y = gelu_f(v4.y);
                v4.z = gelu_f(v4.z); v4.w = gelu_f(v4.w);
            }
            int cc = c4 * 4;
            Rt[(cc + 0) * 132 + r] = v4.x;
            Rt[(cc + 1) * 132 + r] = v4.y;
            Rt[(cc + 2) * 132 + r] = v4.z;
            Rt[(cc + 3) * 132 + r] = v4.w;
        }
        __syncthreads();
#pragma unroll 4
        for (int c = 0; c < 64; ++c) {
            const float4 ra = *(const float4*)&Rt[c * 132 + row0];
            const float4 rb = *(const float4*)&Rt[c * 132 + row0 + 4];
            const float4 wv = *(const float4*)&Wl[c * 64 + col0];
            acc[0][0] += ra.x * wv.x; acc[0][1] += ra.x * wv.y;
            acc[0][2] += ra.x * wv.z; acc[0][3] += ra.x * wv.w;
            acc[1][0] += ra.y * wv.x; acc[1][1] += ra.y * wv.y;
            acc[1][2] += ra.y * wv.z; acc[1][3] += ra.y * wv.w;
            acc[2][0] += ra.z * wv.x; acc[2][1] += ra.z * wv.y;
            acc[2][2] += ra.z * wv.z; acc[2][3] += ra.z * wv.w;
            acc[3][0] += ra.w * wv.x; acc[3][1] += ra.w * wv.y;
            acc[3][2] += ra.w * wv.z; acc[3][3] += ra.w * wv.w;
            acc[4][0] += rb.x * wv.x; acc[4][1] += rb.x * wv.y;
            acc[4][2] += rb.x * wv.z; acc[4][3] += rb.x * wv.w;
            acc[5][0] += rb.y * wv.x; acc[5][1] += rb.y * wv.y;
            acc[5][2] += rb.y * wv.z; acc[5][3] += rb.y * wv.w;
            acc[6][0] += rb.z * wv.x; acc[6][1] += rb.z * wv.y;
            acc[6][2] += rb.z * wv.z; acc[6][3] += rb.z * wv.w;
            acc[7][0] += rb.w * wv.x; acc[7][1] += rb.w * wv.y;
            acc[7][2] += rb.w * wv.z; acc[7][3] += rb.w * wv.w;
        }
    }

    float bv[4];
#pragma unroll
    for (int j = 0; j < 4; ++j) bv[j] = bias[colbase + col0 + j];
    float g = 0.f;
    if (AOUT == 2) g = 1.0f / (1.0f + expf(-gatep[0]));
#pragma unroll
    for (int r = 0; r < 8; ++r) {
        int gr = rowbase + row0 + r;
        if (gr >= nrows) continue;
        size_t base = (size_t)gr * ldout + colbase + col0;
#pragma unroll
        for (int j = 0; j < 4; ++j) {
            float v = acc[r][j] + bv[j];
            if (AOUT == 1) v = fmaxf(v, 0.f);
            if constexpr (sizeof(TOUT) == 2) {
                ((u16*)out)[base + j] = f2bf(v);
            } else {
                float* of = (float*)out;
                if (AOUT == 2) v = g * v + (1.0f - g) * of[base + j];
                of[base + j] = v;
            }
        }
    }
}

// ------- fuse arel into qW: qWA[c, h*16+d] = sum_e qW[c, h*16+e]*arel[h,d,e] --------
__global__ __launch_bounds__(256) void fuse_kernel(
    const float* __restrict__ qW, const float* __restrict__ qb,
    const float* __restrict__ arel, float* __restrict__ qWA, float* __restrict__ qbA)
{
    __shared__ float Al[2048];
    int tid = threadIdx.x;
    for (int i = tid; i < 2048; i += 256) Al[i] = arel[i];
    __syncthreads();
    int idx = blockIdx.x * 256 + tid;      // 64 blocks * 256 = 16384 entries
    int c = idx >> 7, col = idx & 127;
    int h = col >> 4, d = col & 15;
    const float* Ah = &Al[h * 256 + d * 16];
    const float* qr = &qW[(size_t)c * 128 + h * 16];
    float acc = 0.f;
#pragma unroll
    for (int e = 0; e < 16; ++e) acc += qr[e] * Ah[e];
    qWA[idx] = acc;
    if (blockIdx.x == 0 && tid < 128) {
        int h2 = tid >> 4, d2 = tid & 15;
        const float* Ah2 = &Al[h2 * 256 + d2 * 16];
        const float* qb2 = &qb[h2 * 16];
        float accb = 0.f;
#pragma unroll
        for (int e = 0; e < 16; ++e) accb += qb2[e] * Ah2[e];
        qbA[tid] = accb;
    }
}

// ---------------- CSR-gather attention: one wave per destination node ----------------
// kv table: [N][128] u32 — k packed bf16 pairs in lanes 0-63, v in 64-127.
// 4-deep software-pipelined prefetch (groups of 4 edges, ping-pong registers).
__global__ __launch_bounds__(256) void gather_kernel(
    const float* __restrict__ qq, const u32* __restrict__ kv,
    const int* __restrict__ off, const int* __restrict__ csrc,
    const float* __restrict__ prel, const float* __restrict__ mrel,
    float* __restrict__ agg, int N, int accum)
{
    __shared__ float M[2048];   // mrel [h][d][e]
    int tid = threadIdx.x;
    for (int i = tid; i < 2048; i += 256) M[i] = mrel[i];
    __syncthreads();
    int lane = tid & 63, wid = tid >> 6;
    int h = lane >> 3, dp = lane & 7;
    int dst = blockIdx.x * 4 + wid;
    if (dst >= N) return;

    float prl = prel[h] * 0.25f;   // * 1/sqrt(D)
    const float2 qv = *(const float2*)&qq[(size_t)dst * 128 + lane * 2];
    int beg = off[dst], end = off[dst + 1];
    float acc0 = 0.f, acc1 = 0.f, ssum = 0.f;

    u32 kA[4], vA[4], kB[4], vB[4];

    auto LOADG = [&](int g, u32* kk, u32* vv) {
#pragma unroll
        for (int i = 0; i < 4; ++i) {
            int e = g + i;
            int s = (e < end) ? csrc[e] : 0;
            const u32* base = kv + (size_t)s * 128;
            kk[i] = base[lane];
            vv[i] = base[64 + lane];
        }
    };
    auto COMPG = [&](int g, const u32* kk, const u32* vv) {
#pragma unroll
        for (int i = 0; i < 4; ++i) {
            float p = qv.x * lo2f(kk[i]) + qv.y * hi2f(kk[i]);
            p += __shfl_xor(p, 1);
            p += __shfl_xor(p, 2);
            p += __shfl_xor(p, 4);   // 8-lane head reduction
            float sarg = fminf(fmaxf(p * prl, -60.f), 60.f);
            float ex = (g + i < end) ? expf(sarg) : 0.f;
            ssum += ex;
            acc0 += ex * lo2f(vv[i]);
            acc1 += ex * hi2f(vv[i]);
        }
    };

    if (beg < end) {
        LOADG(beg, kA, vA);
        int g = beg;
        for (;;) {
            LOADG(g + 4, kB, vB);       // prefetch next group
            COMPG(g, kA, vA);
            g += 4;
            if (g >= end) break;
            LOADG(g + 4, kA, vA);
            COMPG(g, kB, vB);
            g += 4;
            if (g >= end) break;
        }
    }

    float inv = 1.0f / (ssum + 1e-16f);
    acc0 *= inv; acc1 *= inv;

    // post-aggregation mrel: out[h][e] = sum_d t[h][d]*M[h][d][e]
    float o0 = 0.f, o1 = 0.f;
    const float* Mh = &M[h * 256];
#pragma unroll
    for (int dd = 0; dd < 8; ++dd) {
        float b0 = __shfl(acc0, (h << 3) | dd);   // t[h][2dd]
        float b1 = __shfl(acc1, (h << 3) | dd);   // t[h][2dd+1]
        const float2 m0 = *(const float2*)&Mh[(2 * dd) * 16 + dp * 2];
        const float2 m1 = *(const float2*)&Mh[(2 * dd + 1) * 16 + dp * 2];
        o0 += b0 * m0.x + b1 * m1.x;
        o1 += b0 * m0.y + b1 * m1.y;
    }
    float* ap = &agg[(size_t)dst * 128 + lane * 2];
    if (accum) { ap[0] += o0; ap[1] += o1; }
    else       { ap[0] = o0;  ap[1] = o1;  }
}

// ---------------- CSR build --------------------------------------------------------
__global__ void hist_kernel(const int* __restrict__ dst, int* __restrict__ deg, int E) {
    int i = blockIdx.x * 256 + threadIdx.x;
    if (i < E) atomicAdd(&deg[dst[i]], 1);
}
__global__ __launch_bounds__(1024) void scan_kernel(
    const int* __restrict__ deg, int* __restrict__ off, int N)
{
    __shared__ int s[1024];
    int tid = threadIdx.x;
    int C = (N + 1023) >> 10;
    int b = tid * C;
    int sum = 0;
    for (int i = 0; i < C; ++i) { int idx = b + i; if (idx < N) sum += deg[idx]; }
    s[tid] = sum;
    __syncthreads();
    for (int d = 1; d < 1024; d <<= 1) {
        int t = (tid >= d) ? s[tid - d] : 0;
        __syncthreads();
        s[tid] += t;
        __syncthreads();
    }
    int run = s[tid] - sum;   // exclusive prefix of this chunk
    for (int i = 0; i < C; ++i) {
        int idx = b + i;
        if (idx < N) { off[idx] = run; run += deg[idx]; }
    }
    if (tid == 1023) off[N] = s[1023];
}
__global__ void scatter_kernel(const int* __restrict__ src, const int* __restrict__ dst,
                               const int* __restrict__ off, int* __restrict__ cnt,
                               int* __restrict__ csrc, int E)
{
    int i = blockIdx.x * 256 + threadIdx.x;
    if (i < E) {
        int d = dst[i];
        int pos = off[d] + atomicAdd(&cnt[d], 1);
        csrc[pos] = src[i];
    }
}

// ---------------- L2 normalize: one wave per row, f32 -> f32 ------------------------
__global__ __launch_bounds__(256) void nnorm(
    const float* __restrict__ h0, float* __restrict__ emb, int N)
{
    int lane = threadIdx.x & 63, wid = threadIdx.x >> 6;
    int n = blockIdx.x * 4 + wid;
    if (n >= N) return;
    const float2 v = *(const float2*)&h0[(size_t)n * 128 + lane * 2];
    float s = v.x * v.x + v.y * v.y;
#pragma unroll
    for (int m = 1; m < 64; m <<= 1) s += __shfl_xor(s, m);
    float sc = 1.0f / fmaxf(sqrtf(s), 1e-12f);
    if (!isfinite(sc)) sc = 0.f;
    float2* op = (float2*)&emb[(size_t)n * 128 + lane * 2];
    *op = make_float2(v.x * sc, v.y * sc);
}

// ---------------- sentinel (f32) ----------------------------------------------------
__global__ void sentinel_kernel(float* out, int n, float val) {
    int i = blockIdx.x * 256 + threadIdx.x;
    if (i < n) out[i] = val;
}

extern "C" void kernel_launch(void* const* d_in, const int* in_sizes, int n_in,
                              void* d_out, int out_size, void* d_ws, size_t ws_size,
                              hipStream_t stream)
{
    const int N = in_sizes[0] / (TTYPES * INC);
    const int E = in_sizes[19] / 2;
    const size_t NH = (size_t)N * HID;

    // ws: hbuf 2NH f32 + qqb NH f32 + agg0 NH f32 + kv N*128 u32
    const size_t need = 4 * NH * 4 + NH * 4;   // ~128 MB
    if (ws_size < need) {
        sentinel_kernel<<<(out_size + 255) / 256, 256, 0, stream>>>(
            (float*)d_out, out_size, 30.0f);
        return;
    }

    const float* x     = (const float*)d_in[0];
    const float* encW  = (const float*)d_in[1];
    const float* encb  = (const float*)d_in[2];
    const float* kW    = (const float*)d_in[3];
    const float* kb_   = (const float*)d_in[4];
    const float* qW    = (const float*)d_in[5];
    const float* qb    = (const float*)d_in[6];
    const float* vW    = (const float*)d_in[7];
    const float* vb_   = (const float*)d_in[8];
    const float* aW    = (const float*)d_in[9];
    const float* ab    = (const float*)d_in[10];
    const float* skipw = (const float*)d_in[11];
    const float* arel  = (const float*)d_in[12];
    const float* mrel  = (const float*)d_in[13];
    const float* prel  = (const float*)d_in[14];
    const float* dW1   = (const float*)d_in[15];
    const float* db1   = (const float*)d_in[16];
    const float* dW2   = (const float*)d_in[17];
    const float* db2   = (const float*)d_in[18];

    // ---- ws layout: hbuf[2NH] f32 | qqb NH f32 | agg0 NH f32 | kv [N][128] u32 ----
    float* hbuf = (float*)d_ws;
    float* qqb  = hbuf + 2 * NH;
    float* agg0 = qqb + NH;
    u32* kvbuf  = (u32*)(agg0 + NH);

    // ---- d_out scratch ----
    float* agg1 = (float*)d_out;                 // emb region, dead before nnorm
    int*   ip   = (int*)((float*)d_out + NH);    // rec region
    int* deg = ip;            ip += N;
    int* cnt = ip;            ip += N;
    int* offs[4];  for (int e = 0; e < 4; ++e) { offs[e] = ip; ip += N + 1; }
    int* csrcs[4]; for (int e = 0; e < 4; ++e) { csrcs[e] = ip; ip += E; }
    float* qWA = (float*)ip;
    float* qbA = qWA + HID * HID;

    static const int st_[4] = {0, 1, 0, 1};
    static const int dt_[4] = {1, 0, 0, 1};
    float* aggs[2] = {agg0, agg1};

    const int egrid = (E + 255) / 256;
    const int RT    = (N + 127) / 128;
    const int GW    = (N + 3) / 4;

    // ---- CSR build (once, reused by both layers) ----
    for (int et = 0; et < 4; ++et) {
        const int* ei = (const int*)d_in[19 + et];
        hipMemsetAsync(deg, 0, (size_t)N * 4, stream);
        hist_kernel<<<egrid, 256, 0, stream>>>(ei + E, deg, E);
        scan_kernel<<<1, 1024, 0, stream>>>(deg, offs[et], N);
        hipMemsetAsync(cnt, 0, (size_t)N * 4, stream);
        scatter_kernel<<<egrid, 256, 0, stream>>>(ei, ei + E, offs[et], cnt,
                                                  csrcs[et], E);
    }

    // ---- encoder: h[t] = relu(x[t] @ encW[t] + encb[t]) ----
    for (int t = 0; t < TTYPES; ++t) {
        gemm_kernel<INC, HID, 0, 1, float><<<dim3(RT, 2), 256, 0, stream>>>(
            x + (size_t)t * N * INC, encW + (size_t)t * INC * HID, encb + t * HID,
            hbuf + t * NH, N, nullptr, HID);
    }

    for (int l = 0; l < 2; ++l) {
        // group by SOURCE type; st==0 gathers write agg, st==1 accumulate
        for (int st = 0; st < TTYPES; ++st) {
            int bs = l * 2 + st;
            gemm_kernel<HID, HID, 0, 0, u16><<<dim3(RT, 2), 256, 0, stream>>>(
                hbuf + st * NH, kW + (size_t)bs * HID * HID, kb_ + (size_t)bs * HID,
                (u16*)kvbuf, N, nullptr, 256);          // k -> lanes 0-63
            gemm_kernel<HID, HID, 0, 0, u16><<<dim3(RT, 2), 256, 0, stream>>>(
                hbuf + st * NH, vW + (size_t)bs * HID * HID, vb_ + (size_t)bs * HID,
                (u16*)kvbuf + 128, N, nullptr, 256);    // v -> lanes 64-127
            for (int et = 0; et < 4; ++et) {
                if (st_[et] != st) continue;
                int dt = dt_[et];
                int rel = l * 4 + et;
                int bd  = l * 2 + dt;
                fuse_kernel<<<64, 256, 0, stream>>>(
                    qW + (size_t)bd * HID * HID, qb + (size_t)bd * HID,
                    arel + (size_t)rel * 2048, qWA, qbA);
                gemm_kernel<HID, HID, 0, 0, float><<<dim3(RT, 2), 256, 0, stream>>>(
                    hbuf + dt * NH, qWA, qbA, qqb, N, nullptr, HID);
                gather_kernel<<<GW, 256, 0, stream>>>(
                    qqb, kvbuf, offs[et], csrcs[et],
                    prel + (size_t)rel * HH, mrel + (size_t)rel * 2048,
                    aggs[dt], N, st);
            }
        }
        // h[t] = g*(gelu(agg[t]) @ aW + ab) + (1-g)*h[t]
        for (int t = 0; t < TTYPES; ++t) {
            int b = l * 2 + t;
            gemm_kernel<HID, HID, 1, 2, float><<<dim3(RT, 2), 256, 0, stream>>>(
                aggs[t], aW + (size_t)b * HID * HID, ab + (size_t)b * HID,
                hbuf + t * NH, N, skipw + b, HID);
        }
    }

    float* emb = (float*)d_out;           // [N][128] f32
    float* rec = emb + NH;                // [N][256] f32
    nnorm<<<GW, 256, 0, stream>>>(hbuf, emb, N);
    gemm_kernel<HID, HID, 0, 1, float><<<dim3(RT, 2), 256, 0, stream>>>(
        hbuf, dW1, db1, agg0, N, nullptr, HID);
    gemm_kernel<HID, INC, 0, 0, float><<<dim3(RT, 4), 256, 0, stream>>>(
        agg0, dW2, db2, rec, N, nullptr, INC);
}

// Round 16
// 1954.326 us; speedup vs baseline: 1.3921x; 1.2856x over previous
//
#include <hip/hip_runtime.h>
#include <hip/hip_bf16.h>

// HGT forward, MI355X — ROUND 16: hierarchical CSR scan (was 96µs single-block)
// + MFMA bf16 16x16x32 GEMM for q/k/v projections (encoder/a/decoder stay f32).
// CSR-gather attention (4-deep prefetch), folded arel, post-agg mrel, f32 outputs.

#define HH 8
#define HID 128
#define INC 256
#define TTYPES 2

typedef unsigned short u16;
typedef unsigned int u32;
typedef __attribute__((ext_vector_type(8))) short short8v;
typedef __attribute__((ext_vector_type(4))) float f32x4;

__device__ __forceinline__ float lo2f(u32 u) { return __uint_as_float(u << 16); }
__device__ __forceinline__ float hi2f(u32 u) { return __uint_as_float(u & 0xffff0000u); }
__device__ __forceinline__ u16 f2bf(float f) {
    u32 i = __float_as_uint(f);
    u32 r = i + 0x7fffu + ((i >> 16) & 1u);   // RNE
    return (u16)(r >> 16);
}
__device__ __forceinline__ float gelu_f(float x) {
    return 0.5f * x * (1.0f + erff(x * 0.7071067811865476f));
}

// ---------------- MFMA GEMM: [nrows x 128] x [128 x 128], bf16 inputs f32 accum -----
// Per block: 4 waves, each computes a 16-row x 128-col strip. W staged to LDS
// transposed [col][k] bf16 (stride 136 = 16B-aligned rows, ~2-way bank alias).
// A frag: lane reads 8 consecutive k of row (lane&15), k-group (lane>>4)*8.
// D frag: col = lane&15, row = (lane>>4)*4 + reg (guide-verified mapping).
template <typename TOUT>
__global__ __launch_bounds__(256) void mgemm_kernel(
    const float* __restrict__ in, const float* __restrict__ W,
    const float* __restrict__ bias, TOUT* __restrict__ out,
    int nrows, int ldout)
{
    __shared__ u16 Wt[128 * 136];
    const int tid = threadIdx.x;
    for (int i = tid; i < 128 * 32; i += 256) {
        int k = i >> 5, c4 = (i & 31) << 2;
        const float4 w = *(const float4*)&W[(size_t)k * 128 + c4];
        Wt[(c4 + 0) * 136 + k] = f2bf(w.x);
        Wt[(c4 + 1) * 136 + k] = f2bf(w.y);
        Wt[(c4 + 2) * 136 + k] = f2bf(w.z);
        Wt[(c4 + 3) * 136 + k] = f2bf(w.w);
    }
    __syncthreads();

    const int lane = tid & 63, wid = tid >> 6;
    const int row0 = blockIdx.x * 64 + wid * 16;
    const int rsub = lane & 15;
    const int kgrp = (lane >> 4) * 8;
    const int arow = row0 + rsub;
    const int asrc = (arow < nrows) ? arow : (nrows > 0 ? nrows - 1 : 0);

    f32x4 acc[8];
#pragma unroll
    for (int t = 0; t < 8; ++t) acc[t] = (f32x4){0.f, 0.f, 0.f, 0.f};

#pragma unroll
    for (int ks = 0; ks < 4; ++ks) {
        const int k0 = ks * 32 + kgrp;
        const float* ap = in + (size_t)asrc * 128 + k0;
        const float4 a0 = *(const float4*)ap;
        const float4 a1 = *(const float4*)(ap + 4);
        short8v a;
        a[0] = (short)f2bf(a0.x); a[1] = (short)f2bf(a0.y);
        a[2] = (short)f2bf(a0.z); a[3] = (short)f2bf(a0.w);
        a[4] = (short)f2bf(a1.x); a[5] = (short)f2bf(a1.y);
        a[6] = (short)f2bf(a1.z); a[7] = (short)f2bf(a1.w);
#pragma unroll
        for (int ct = 0; ct < 8; ++ct) {
            const short8v b = *(const short8v*)&Wt[(ct * 16 + rsub) * 136 + k0];
            acc[ct] = __builtin_amdgcn_mfma_f32_16x16x32_bf16(a, b, acc[ct], 0, 0, 0);
        }
    }

    const int orow0 = row0 + (lane >> 4) * 4;
#pragma unroll
    for (int ct = 0; ct < 8; ++ct) {
        const int col = ct * 16 + rsub;
        const float bv = bias[col];
#pragma unroll
        for (int r = 0; r < 4; ++r) {
            const int orow = orow0 + r;
            if (orow >= nrows) continue;
            const float v = acc[ct][r] + bv;
            if constexpr (sizeof(TOUT) == 2) {
                ((u16*)out)[(size_t)orow * ldout + col] = f2bf(v);
            } else {
                ((float*)out)[(size_t)orow * ldout + col] = v;
            }
        }
    }
}

// ---------------- Tiled f32 GEMM: 128x64 tile, 8x4 microtile (enc/a/dec) ------------
// AIN: 0 none, 1 gelu. AOUT: 0 none, 1 relu, 2 skip blend out = g*v + (1-g)*out_old.
template <int CIN, int COUT, int AIN, int AOUT, typename TOUT>
__global__ __launch_bounds__(256) void gemm_kernel(
    const float* __restrict__ in, const float* __restrict__ W,
    const float* __restrict__ bias, TOUT* __restrict__ out, int nrows,
    const float* __restrict__ gatep, int ldout)
{
    __shared__ __align__(16) float Wl[64 * 64];
    __shared__ __align__(16) float Rt[64 * 132];
    const int tid = threadIdx.x;
    const int rowbase = blockIdx.x * 128;
    const int colbase = blockIdx.y * 64;

    const int tcol = tid & 15;
    const int trow = tid >> 4;
    const int col0 = tcol * 4;
    const int row0 = trow * 8;
    float acc[8][4] = {};

    for (int kc = 0; kc < CIN; kc += 64) {
        __syncthreads();
        for (int i = tid; i < 64 * 16; i += 256) {
            int r = i >> 4, j4 = i & 15;
            ((float4*)Wl)[r * 16 + j4] =
                *(const float4*)&W[(size_t)(kc + r) * COUT + colbase + j4 * 4];
        }
        for (int i = tid; i < 128 * 16; i += 256) {
            int r = i >> 4, c4 = i & 15;
            int gr = rowbase + r;
            float4 v4 = make_float4(0.f, 0.f, 0.f, 0.f);
            if (gr < nrows) v4 = *(const float4*)&in[(size_t)gr * CIN + kc + c4 * 4];
            if (AIN == 1) {
                v4.x = gelu_f(v4.x); v4.y = gelu_f(v4.y);
                v4.z = gelu_f(v4.z); v4.w = gelu_f(v4.w);
            }
            int cc = c4 * 4;
            Rt[(cc + 0) * 132 + r] = v4.x;
            Rt[(cc + 1) * 132 + r] = v4.y;
            Rt[(cc + 2) * 132 + r] = v4.z;
            Rt[(cc + 3) * 132 + r] = v4.w;
        }
        __syncthreads();
#pragma unroll 4
        for (int c = 0; c < 64; ++c) {
            const float4 ra = *(const float4*)&Rt[c * 132 + row0];
            const float4 rb = *(const float4*)&Rt[c * 132 + row0 + 4];
            const float4 wv = *(const float4*)&Wl[c * 64 + col0];
            acc[0][0] += ra.x * wv.x; acc[0][1] += ra.x * wv.y;
            acc[0][2] += ra.x * wv.z; acc[0][3] += ra.x * wv.w;
            acc[1][0] += ra.y * wv.x; acc[1][1] += ra.y * wv.y;
            acc[1][2] += ra.y * wv.z; acc[1][3] += ra.y * wv.w;
            acc[2][0] += ra.z * wv.x; acc[2][1] += ra.z * wv.y;
            acc[2][2] += ra.z * wv.z; acc[2][3] += ra.z * wv.w;
            acc[3][0] += ra.w * wv.x; acc[3][1] += ra.w * wv.y;
            acc[3][2] += ra.w * wv.z; acc[3][3] += ra.w * wv.w;
            acc[4][0] += rb.x * wv.x; acc[4][1] += rb.x * wv.y;
            acc[4][2] += rb.x * wv.z; acc[4][3] += rb.x * wv.w;
            acc[5][0] += rb.y * wv.x; acc[5][1] += rb.y * wv.y;
            acc[5][2] += rb.y * wv.z; acc[5][3] += rb.y * wv.w;
            acc[6][0] += rb.z * wv.x; acc[6][1] += rb.z * wv.y;
            acc[6][2] += rb.z * wv.z; acc[6][3] += rb.z * wv.w;
            acc[7][0] += rb.w * wv.x; acc[7][1] += rb.w * wv.y;
            acc[7][2] += rb.w * wv.z; acc[7][3] += rb.w * wv.w;
        }
    }

    float bv[4];
#pragma unroll
    for (int j = 0; j < 4; ++j) bv[j] = bias[colbase + col0 + j];
    float g = 0.f;
    if (AOUT == 2) g = 1.0f / (1.0f + expf(-gatep[0]));
#pragma unroll
    for (int r = 0; r < 8; ++r) {
        int gr = rowbase + row0 + r;
        if (gr >= nrows) continue;
        size_t base = (size_t)gr * ldout + colbase + col0;
#pragma unroll
        for (int j = 0; j < 4; ++j) {
            float v = acc[r][j] + bv[j];
            if (AOUT == 1) v = fmaxf(v, 0.f);
            if constexpr (sizeof(TOUT) == 2) {
                ((u16*)out)[base + j] = f2bf(v);
            } else {
                float* of = (float*)out;
                if (AOUT == 2) v = g * v + (1.0f - g) * of[base + j];
                of[base + j] = v;
            }
        }
    }
}

// ------- fuse arel into qW: qWA[c, h*16+d] = sum_e qW[c, h*16+e]*arel[h,d,e] --------
__global__ __launch_bounds__(256) void fuse_kernel(
    const float* __restrict__ qW, const float* __restrict__ qb,
    const float* __restrict__ arel, float* __restrict__ qWA, float* __restrict__ qbA)
{
    __shared__ float Al[2048];
    int tid = threadIdx.x;
    for (int i = tid; i < 2048; i += 256) Al[i] = arel[i];
    __syncthreads();
    int idx = blockIdx.x * 256 + tid;
    int c = idx >> 7, col = idx & 127;
    int h = col >> 4, d = col & 15;
    const float* Ah = &Al[h * 256 + d * 16];
    const float* qr = &qW[(size_t)c * 128 + h * 16];
    float acc = 0.f;
#pragma unroll
    for (int e = 0; e < 16; ++e) acc += qr[e] * Ah[e];
    qWA[idx] = acc;
    if (blockIdx.x == 0 && tid < 128) {
        int h2 = tid >> 4, d2 = tid & 15;
        const float* Ah2 = &Al[h2 * 256 + d2 * 16];
        const float* qb2 = &qb[h2 * 16];
        float accb = 0.f;
#pragma unroll
        for (int e = 0; e < 16; ++e) accb += qb2[e] * Ah2[e];
        qbA[tid] = accb;
    }
}

// ---------------- CSR-gather attention: one wave per destination node ----------------
// kv: [N][128] u32 — k packed bf16 pairs lanes 0-63, v lanes 64-127. 4-deep prefetch.
__global__ __launch_bounds__(256) void gather_kernel(
    const float* __restrict__ qq, const u32* __restrict__ kv,
    const int* __restrict__ off, const int* __restrict__ csrc,
    const float* __restrict__ prel, const float* __restrict__ mrel,
    float* __restrict__ agg, int N, int accum)
{
    __shared__ float M[2048];
    int tid = threadIdx.x;
    for (int i = tid; i < 2048; i += 256) M[i] = mrel[i];
    __syncthreads();
    int lane = tid & 63, wid = tid >> 6;
    int h = lane >> 3, dp = lane & 7;
    int dst = blockIdx.x * 4 + wid;
    if (dst >= N) return;

    float prl = prel[h] * 0.25f;
    const float2 qv = *(const float2*)&qq[(size_t)dst * 128 + lane * 2];
    int beg = off[dst], end = off[dst + 1];
    float acc0 = 0.f, acc1 = 0.f, ssum = 0.f;

    u32 kA[4], vA[4], kB[4], vB[4];

    auto LOADG = [&](int g, u32* kk, u32* vv) {
#pragma unroll
        for (int i = 0; i < 4; ++i) {
            int e = g + i;
            int s = (e < end) ? csrc[e] : 0;
            const u32* base = kv + (size_t)s * 128;
            kk[i] = base[lane];
            vv[i] = base[64 + lane];
        }
    };
    auto COMPG = [&](int g, const u32* kk, const u32* vv) {
#pragma unroll
        for (int i = 0; i < 4; ++i) {
            float p = qv.x * lo2f(kk[i]) + qv.y * hi2f(kk[i]);
            p += __shfl_xor(p, 1);
            p += __shfl_xor(p, 2);
            p += __shfl_xor(p, 4);
            float sarg = fminf(fmaxf(p * prl, -60.f), 60.f);
            float ex = (g + i < end) ? expf(sarg) : 0.f;
            ssum += ex;
            acc0 += ex * lo2f(vv[i]);
            acc1 += ex * hi2f(vv[i]);
        }
    };

    if (beg < end) {
        LOADG(beg, kA, vA);
        int g = beg;
        for (;;) {
            LOADG(g + 4, kB, vB);
            COMPG(g, kA, vA);
            g += 4;
            if (g >= end) break;
            LOADG(g + 4, kA, vA);
            COMPG(g, kB, vB);
            g += 4;
            if (g >= end) break;
        }
    }

    float inv = 1.0f / (ssum + 1e-16f);
    acc0 *= inv; acc1 *= inv;

    float o0 = 0.f, o1 = 0.f;
    const float* Mh = &M[h * 256];
#pragma unroll
    for (int dd = 0; dd < 8; ++dd) {
        float b0 = __shfl(acc0, (h << 3) | dd);
        float b1 = __shfl(acc1, (h << 3) | dd);
        const float2 m0 = *(const float2*)&Mh[(2 * dd) * 16 + dp * 2];
        const float2 m1 = *(const float2*)&Mh[(2 * dd + 1) * 16 + dp * 2];
        o0 += b0 * m0.x + b1 * m1.x;
        o1 += b0 * m0.y + b1 * m1.y;
    }
    float* ap = &agg[(size_t)dst * 128 + lane * 2];
    if (accum) { ap[0] += o0; ap[1] += o1; }
    else       { ap[0] = o0;  ap[1] = o1;  }
}

// ---------------- CSR build: hist + hierarchical scan + scatter ---------------------
__global__ void hist_kernel(const int* __restrict__ dst, int* __restrict__ deg, int E) {
    int i = blockIdx.x * 256 + threadIdx.x;
    if (i < E) atomicAdd(&deg[dst[i]], 1);
}
// pass 1: per-1024-chunk sums
__global__ __launch_bounds__(256) void scan_part(const int* __restrict__ deg,
                                                 int* __restrict__ bsum, int N) {
    int b = blockIdx.x, tid = threadIdx.x;
    int base = b * 1024 + tid * 4;
    int s = 0;
#pragma unroll
    for (int i = 0; i < 4; ++i) { int idx = base + i; if (idx < N) s += deg[idx]; }
    __shared__ int sm[256];
    sm[tid] = s; __syncthreads();
    for (int d = 128; d > 0; d >>= 1) {
        if (tid < d) sm[tid] += sm[tid + d];
        __syncthreads();
    }
    if (tid == 0) bsum[b] = sm[0];
}
// pass 2: exclusive scan of chunk sums (NB <= 256) + write off[N]=total
__global__ __launch_bounds__(256) void scan_top(int* __restrict__ bsum,
                                                int* __restrict__ off, int NB, int N) {
    __shared__ int sm[256];
    int tid = threadIdx.x;
    int v = (tid < NB) ? bsum[tid] : 0;
    sm[tid] = v; __syncthreads();
    for (int d = 1; d < 256; d <<= 1) {
        int t = (tid >= d) ? sm[tid - d] : 0;
        __syncthreads();
        sm[tid] += t;
        __syncthreads();
    }
    if (tid < NB) bsum[tid] = sm[tid] - v;   // exclusive
    if (tid == 255) off[N] = sm[255];        // grand total
}
// pass 3: per-chunk exclusive scan + chunk offset
__global__ __launch_bounds__(256) void scan_fin(const int* __restrict__ deg,
                                                const int* __restrict__ bsum,
                                                int* __restrict__ off, int N) {
    int b = blockIdx.x, tid = threadIdx.x;
    int base = b * 1024 + tid * 4;
    int v[4]; int s = 0;
#pragma unroll
    for (int i = 0; i < 4; ++i) {
        int idx = base + i;
        v[i] = (idx < N) ? deg[idx] : 0;
        s += v[i];
    }
    __shared__ int sm[256];
    sm[tid] = s; __syncthreads();
    for (int d = 1; d < 256; d <<= 1) {
        int t = (tid >= d) ? sm[tid - d] : 0;
        __syncthreads();
        sm[tid] += t;
        __syncthreads();
    }
    int run = bsum[b] + sm[tid] - s;
#pragma unroll
    for (int i = 0; i < 4; ++i) {
        int idx = base + i;
        if (idx < N) { off[idx] = run; run += v[i]; }
    }
}
__global__ void scatter_kernel(const int* __restrict__ src, const int* __restrict__ dst,
                               const int* __restrict__ off, int* __restrict__ cnt,
                               int* __restrict__ csrc, int E)
{
    int i = blockIdx.x * 256 + threadIdx.x;
    if (i < E) {
        int d = dst[i];
        int pos = off[d] + atomicAdd(&cnt[d], 1);
        csrc[pos] = src[i];
    }
}

// ---------------- L2 normalize: one wave per row, f32 -> f32 ------------------------
__global__ __launch_bounds__(256) void nnorm(
    const float* __restrict__ h0, float* __restrict__ emb, int N)
{
    int lane = threadIdx.x & 63, wid = threadIdx.x >> 6;
    int n = blockIdx.x * 4 + wid;
    if (n >= N) return;
    const float2 v = *(const float2*)&h0[(size_t)n * 128 + lane * 2];
    float s = v.x * v.x + v.y * v.y;
#pragma unroll
    for (int m = 1; m < 64; m <<= 1) s += __shfl_xor(s, m);
    float sc = 1.0f / fmaxf(sqrtf(s), 1e-12f);
    if (!isfinite(sc)) sc = 0.f;
    float2* op = (float2*)&emb[(size_t)n * 128 + lane * 2];
    *op = make_float2(v.x * sc, v.y * sc);
}

// ---------------- sentinel (f32) ----------------------------------------------------
__global__ void sentinel_kernel(float* out, int n, float val) {
    int i = blockIdx.x * 256 + threadIdx.x;
    if (i < n) out[i] = val;
}

extern "C" void kernel_launch(void* const* d_in, const int* in_sizes, int n_in,
                              void* d_out, int out_size, void* d_ws, size_t ws_size,
                              hipStream_t stream)
{
    const int N = in_sizes[0] / (TTYPES * INC);
    const int E = in_sizes[19] / 2;
    const size_t NH = (size_t)N * HID;

    const size_t need = 4 * NH * 4 + NH * 4;   // ~128 MB
    if (ws_size < need) {
        sentinel_kernel<<<(out_size + 255) / 256, 256, 0, stream>>>(
            (float*)d_out, out_size, 30.0f);
        return;
    }

    const float* x     = (const float*)d_in[0];
    const float* encW  = (const float*)d_in[1];
    const float* encb  = (const float*)d_in[2];
    const float* kW    = (const float*)d_in[3];
    const float* kb_   = (const float*)d_in[4];
    const float* qW    = (const float*)d_in[5];
    const float* qb    = (const float*)d_in[6];
    const float* vW    = (const float*)d_in[7];
    const float* vb_   = (const float*)d_in[8];
    const float* aW    = (const float*)d_in[9];
    const float* ab    = (const float*)d_in[10];
    const float* skipw = (const float*)d_in[11];
    const float* arel  = (const float*)d_in[12];
    const float* mrel  = (const float*)d_in[13];
    const float* prel  = (const float*)d_in[14];
    const float* dW1   = (const float*)d_in[15];
    const float* db1   = (const float*)d_in[16];
    const float* dW2   = (const float*)d_in[17];
    const float* db2   = (const float*)d_in[18];

    // ---- ws layout: hbuf[2NH] f32 | qqb NH f32 | agg0 NH f32 | kv [N][128] u32 ----
    float* hbuf = (float*)d_ws;
    float* qqb  = hbuf + 2 * NH;
    float* agg0 = qqb + NH;
    u32* kvbuf  = (u32*)(agg0 + NH);

    // ---- d_out scratch ----
    float* agg1 = (float*)d_out;                 // emb region, dead before nnorm
    int*   ip   = (int*)((float*)d_out + NH);    // rec region
    int* deg = ip;            ip += N;
    int* cnt = ip;            ip += N;
    int* offs[4];  for (int e = 0; e < 4; ++e) { offs[e] = ip; ip += N + 1; }
    int* csrcs[4]; for (int e = 0; e < 4; ++e) { csrcs[e] = ip; ip += E; }
    float* qWA = (float*)ip;
    float* qbA = qWA + HID * HID;
    int* bsum  = (int*)(qbA + HID);

    static const int st_[4] = {0, 1, 0, 1};
    static const int dt_[4] = {1, 0, 0, 1};
    float* aggs[2] = {agg0, agg1};

    const int egrid = (E + 255) / 256;
    const int RT    = (N + 127) / 128;
    const int MG    = (N + 63) / 64;
    const int GW    = (N + 3) / 4;
    const int NB1   = (N + 1023) >> 10;

    // ---- CSR build (once, reused by both layers) ----
    for (int et = 0; et < 4; ++et) {
        const int* ei = (const int*)d_in[19 + et];
        hipMemsetAsync(deg, 0, (size_t)N * 4, stream);
        hist_kernel<<<egrid, 256, 0, stream>>>(ei + E, deg, E);
        scan_part<<<NB1, 256, 0, stream>>>(deg, bsum, N);
        scan_top<<<1, 256, 0, stream>>>(bsum, offs[et], NB1, N);
        scan_fin<<<NB1, 256, 0, stream>>>(deg, bsum, offs[et], N);
        hipMemsetAsync(cnt, 0, (size_t)N * 4, stream);
        scatter_kernel<<<egrid, 256, 0, stream>>>(ei, ei + E, offs[et], cnt,
                                                  csrcs[et], E);
    }

    // ---- encoder: h[t] = relu(x[t] @ encW[t] + encb[t])  (f32 vector GEMM) ----
    for (int t = 0; t < TTYPES; ++t) {
        gemm_kernel<INC, HID, 0, 1, float><<<dim3(RT, 2), 256, 0, stream>>>(
            x + (size_t)t * N * INC, encW + (size_t)t * INC * HID, encb + t * HID,
            hbuf + t * NH, N, nullptr, HID);
    }

    for (int l = 0; l < 2; ++l) {
        // group by SOURCE type; st==0 gathers write agg, st==1 accumulate
        for (int st = 0; st < TTYPES; ++st) {
            int bs = l * 2 + st;
            mgemm_kernel<u16><<<MG, 256, 0, stream>>>(
                hbuf + st * NH, kW + (size_t)bs * HID * HID, kb_ + (size_t)bs * HID,
                (u16*)kvbuf, N, 256);            // k -> lanes 0-63
            mgemm_kernel<u16><<<MG, 256, 0, stream>>>(
                hbuf + st * NH, vW + (size_t)bs * HID * HID, vb_ + (size_t)bs * HID,
                (u16*)kvbuf + 128, N, 256);      // v -> lanes 64-127
            for (int et = 0; et < 4; ++et) {
                if (st_[et] != st) continue;
                int dt = dt_[et];
                int rel = l * 4 + et;
                int bd  = l * 2 + dt;
                fuse_kernel<<<64, 256, 0, stream>>>(
                    qW + (size_t)bd * HID * HID, qb + (size_t)bd * HID,
                    arel + (size_t)rel * 2048, qWA, qbA);
                mgemm_kernel<float><<<MG, 256, 0, stream>>>(
                    hbuf + dt * NH, qWA, qbA, qqb, N, HID);
                gather_kernel<<<GW, 256, 0, stream>>>(
                    qqb, kvbuf, offs[et], csrcs[et],
                    prel + (size_t)rel * HH, mrel + (size_t)rel * 2048,
                    aggs[dt], N, st);
            }
        }
        // h[t] = g*(gelu(agg[t]) @ aW + ab) + (1-g)*h[t]  (f32 vector GEMM)
        for (int t = 0; t < TTYPES; ++t) {
            int b = l * 2 + t;
            gemm_kernel<HID, HID, 1, 2, float><<<dim3(RT, 2), 256, 0, stream>>>(
                aggs[t], aW + (size_t)b * HID * HID, ab + (size_t)b * HID,
                hbuf + t * NH, N, skipw + b, HID);
        }
    }

    float* emb = (float*)d_out;           // [N][128] f32
    float* rec = emb + NH;                // [N][256] f32
    nnorm<<<GW, 256, 0, stream>>>(hbuf, emb, N);
    gemm_kernel<HID, HID, 0, 1, float><<<dim3(RT, 2), 256, 0, stream>>>(
        hbuf, dW1, db1, agg0, N, nullptr, HID);
    gemm_kernel<HID, INC, 0, 0, float><<<dim3(RT, 4), 256, 0, stream>>>(
        agg0, dW2, db2, rec, N, nullptr, INC);
}

// Round 17
// 1707.664 us; speedup vs baseline: 1.5931x; 1.1444x over previous
//
#include <hip/hip_runtime.h>
#include <hip/hip_bf16.h>

// HGT forward, MI355X — ROUND 17: ALL GEMMs on MFMA (generalized chunked kernel,
// 128 rows/block, bf16 fragments, f32 epilogue w/ relu|gelu-in|skip-blend),
// packed-bf16 qq, hierarchical scan, CSR-gather attention (4-deep prefetch).

#define HH 8
#define HID 128
#define INC 256
#define TTYPES 2

typedef unsigned short u16;
typedef unsigned int u32;
typedef __attribute__((ext_vector_type(8))) short short8v;
typedef __attribute__((ext_vector_type(4))) float f32x4;

__device__ __forceinline__ float lo2f(u32 u) { return __uint_as_float(u << 16); }
__device__ __forceinline__ float hi2f(u32 u) { return __uint_as_float(u & 0xffff0000u); }
__device__ __forceinline__ u16 f2bf(float f) {
    u32 i = __float_as_uint(f);
    u32 r = i + 0x7fffu + ((i >> 16) & 1u);   // RNE
    return (u16)(r >> 16);
}
__device__ __forceinline__ float gelu_f(float x) {
    return 0.5f * x * (1.0f + erff(x * 0.7071067811865476f));
}

// ---------------- Generalized MFMA GEMM (bf16 frags, f32 accum/epilogue) ------------
// [nrows x CIN] @ [CIN x COUT]; 128 rows/block (2 sub-tiles x 4 waves x 16 rows).
// W staged per 128x128 chunk to LDS transposed [col][k] bf16 stride 136.
// AIN: 0 none, 1 gelu. AOUT: 0 none, 1 relu, 2 skip blend (f32 out only).
template <int CIN, int COUT, int AIN, int AOUT, typename TOUT>
__global__ __launch_bounds__(256) void mgemm_kernel(
    const float* __restrict__ in, const float* __restrict__ W,
    const float* __restrict__ bias, TOUT* __restrict__ out,
    int nrows, const float* __restrict__ gatep, int ldout)
{
    __shared__ u16 Wt[128 * 136];
    const int tid = threadIdx.x;
    const int lane = tid & 63, wid = tid >> 6;
    const int rsub = lane & 15;
    const int kgrp = (lane >> 4) * 8;
    const int rowblk = blockIdx.x * 128;

    float g = 0.f;
    if (AOUT == 2) g = 1.0f / (1.0f + expf(-gatep[0]));

#pragma unroll
    for (int cc = 0; cc < COUT; cc += 128) {
        f32x4 acc[2][8];
#pragma unroll
        for (int t2 = 0; t2 < 2; ++t2)
#pragma unroll
            for (int ct = 0; ct < 8; ++ct) acc[t2][ct] = (f32x4){0.f, 0.f, 0.f, 0.f};

#pragma unroll
        for (int kc = 0; kc < CIN; kc += 128) {
            __syncthreads();
            for (int i = tid; i < 128 * 32; i += 256) {   // stage W chunk, transposed
                int k = i >> 5, c4 = (i & 31) << 2;
                const float4 w = *(const float4*)&W[(size_t)(kc + k) * COUT + cc + c4];
                Wt[(c4 + 0) * 136 + k] = f2bf(w.x);
                Wt[(c4 + 1) * 136 + k] = f2bf(w.y);
                Wt[(c4 + 2) * 136 + k] = f2bf(w.z);
                Wt[(c4 + 3) * 136 + k] = f2bf(w.w);
            }
            __syncthreads();
#pragma unroll
            for (int t2 = 0; t2 < 2; ++t2) {
                const int arow = rowblk + t2 * 64 + wid * 16 + rsub;
                const int asrc = (arow < nrows) ? arow : (nrows - 1);
                const float* ap0 = in + (size_t)asrc * CIN + kc;
#pragma unroll
                for (int ks = 0; ks < 4; ++ks) {
                    const int k0 = ks * 32 + kgrp;
                    const float4 a0 = *(const float4*)(ap0 + k0);
                    const float4 a1 = *(const float4*)(ap0 + k0 + 4);
                    float av[8] = {a0.x, a0.y, a0.z, a0.w, a1.x, a1.y, a1.z, a1.w};
                    short8v a;
#pragma unroll
                    for (int j = 0; j < 8; ++j) {
                        float xv = av[j];
                        if (AIN == 1) xv = gelu_f(xv);
                        a[j] = (short)f2bf(xv);
                    }
#pragma unroll
                    for (int ct = 0; ct < 8; ++ct) {
                        const short8v b =
                            *(const short8v*)&Wt[(ct * 16 + rsub) * 136 + k0];
                        acc[t2][ct] = __builtin_amdgcn_mfma_f32_16x16x32_bf16(
                            a, b, acc[t2][ct], 0, 0, 0);
                    }
                }
            }
        }
        // epilogue for this col chunk
#pragma unroll
        for (int t2 = 0; t2 < 2; ++t2) {
            const int orow0 = rowblk + t2 * 64 + wid * 16 + (lane >> 4) * 4;
#pragma unroll
            for (int ct = 0; ct < 8; ++ct) {
                const int col = cc + ct * 16 + rsub;
                const float bv = bias[col];
#pragma unroll
                for (int r = 0; r < 4; ++r) {
                    const int orow = orow0 + r;
                    if (orow >= nrows) continue;
                    float v = acc[t2][ct][r] + bv;
                    if (AOUT == 1) v = fmaxf(v, 0.f);
                    size_t o = (size_t)orow * ldout + col;
                    if constexpr (sizeof(TOUT) == 2) {
                        ((u16*)out)[o] = f2bf(v);
                    } else {
                        float* of = (float*)out;
                        if (AOUT == 2) v = g * v + (1.0f - g) * of[o];
                        of[o] = v;
                    }
                }
            }
        }
    }
}

// ------- fuse arel into qW: qWA[c, h*16+d] = sum_e qW[c, h*16+e]*arel[h,d,e] --------
__global__ __launch_bounds__(256) void fuse_kernel(
    const float* __restrict__ qW, const float* __restrict__ qb,
    const float* __restrict__ arel, float* __restrict__ qWA, float* __restrict__ qbA)
{
    __shared__ float Al[2048];
    int tid = threadIdx.x;
    for (int i = tid; i < 2048; i += 256) Al[i] = arel[i];
    __syncthreads();
    int idx = blockIdx.x * 256 + tid;
    int c = idx >> 7, col = idx & 127;
    int h = col >> 4, d = col & 15;
    const float* Ah = &Al[h * 256 + d * 16];
    const float* qr = &qW[(size_t)c * 128 + h * 16];
    float acc = 0.f;
#pragma unroll
    for (int e = 0; e < 16; ++e) acc += qr[e] * Ah[e];
    qWA[idx] = acc;
    if (blockIdx.x == 0 && tid < 128) {
        int h2 = tid >> 4, d2 = tid & 15;
        const float* Ah2 = &Al[h2 * 256 + d2 * 16];
        const float* qb2 = &qb[h2 * 16];
        float accb = 0.f;
#pragma unroll
        for (int e = 0; e < 16; ++e) accb += qb2[e] * Ah2[e];
        qbA[tid] = accb;
    }
}

// ---------------- CSR-gather attention: one wave per destination node ----------------
// kv: [N][128] u32 (k lanes 0-63, v lanes 64-127); qq packed bf16 [N][64] u32.
__global__ __launch_bounds__(256) void gather_kernel(
    const u32* __restrict__ qq, const u32* __restrict__ kv,
    const int* __restrict__ off, const int* __restrict__ csrc,
    const float* __restrict__ prel, const float* __restrict__ mrel,
    float* __restrict__ agg, int N, int accum)
{
    __shared__ float M[2048];
    int tid = threadIdx.x;
    for (int i = tid; i < 2048; i += 256) M[i] = mrel[i];
    __syncthreads();
    int lane = tid & 63, wid = tid >> 6;
    int h = lane >> 3, dp = lane & 7;
    int dst = blockIdx.x * 4 + wid;
    if (dst >= N) return;

    float prl = prel[h] * 0.25f;
    const u32 qu = qq[(size_t)dst * 64 + lane];
    const float qx = lo2f(qu), qy = hi2f(qu);
    int beg = off[dst], end = off[dst + 1];
    float acc0 = 0.f, acc1 = 0.f, ssum = 0.f;

    u32 kA[4], vA[4], kB[4], vB[4];

    auto LOADG = [&](int g, u32* kk, u32* vv) {
#pragma unroll
        for (int i = 0; i < 4; ++i) {
            int e = g + i;
            int s = (e < end) ? csrc[e] : 0;
            const u32* base = kv + (size_t)s * 128;
            kk[i] = base[lane];
            vv[i] = base[64 + lane];
        }
    };
    auto COMPG = [&](int g, const u32* kk, const u32* vv) {
#pragma unroll
        for (int i = 0; i < 4; ++i) {
            float p = qx * lo2f(kk[i]) + qy * hi2f(kk[i]);
            p += __shfl_xor(p, 1);
            p += __shfl_xor(p, 2);
            p += __shfl_xor(p, 4);
            float sarg = fminf(fmaxf(p * prl, -60.f), 60.f);
            float ex = (g + i < end) ? expf(sarg) : 0.f;
            ssum += ex;
            acc0 += ex * lo2f(vv[i]);
            acc1 += ex * hi2f(vv[i]);
        }
    };

    if (beg < end) {
        LOADG(beg, kA, vA);
        int g = beg;
        for (;;) {
            LOADG(g + 4, kB, vB);
            COMPG(g, kA, vA);
            g += 4;
            if (g >= end) break;
            LOADG(g + 4, kA, vA);
            COMPG(g, kB, vB);
            g += 4;
            if (g >= end) break;
        }
    }

    float inv = 1.0f / (ssum + 1e-16f);
    acc0 *= inv; acc1 *= inv;

    float o0 = 0.f, o1 = 0.f;
    const float* Mh = &M[h * 256];
#pragma unroll
    for (int dd = 0; dd < 8; ++dd) {
        float b0 = __shfl(acc0, (h << 3) | dd);
        float b1 = __shfl(acc1, (h << 3) | dd);
        const float2 m0 = *(const float2*)&Mh[(2 * dd) * 16 + dp * 2];
        const float2 m1 = *(const float2*)&Mh[(2 * dd + 1) * 16 + dp * 2];
        o0 += b0 * m0.x + b1 * m1.x;
        o1 += b0 * m0.y + b1 * m1.y;
    }
    float* ap = &agg[(size_t)dst * 128 + lane * 2];
    if (accum) { ap[0] += o0; ap[1] += o1; }
    else       { ap[0] = o0;  ap[1] = o1;  }
}

// ---------------- CSR build: hist + hierarchical scan + scatter ---------------------
__global__ void hist_kernel(const int* __restrict__ dst, int* __restrict__ deg, int E) {
    int i = blockIdx.x * 256 + threadIdx.x;
    if (i < E) atomicAdd(&deg[dst[i]], 1);
}
__global__ __launch_bounds__(256) void scan_part(const int* __restrict__ deg,
                                                 int* __restrict__ bsum, int N) {
    int b = blockIdx.x, tid = threadIdx.x;
    int base = b * 1024 + tid * 4;
    int s = 0;
#pragma unroll
    for (int i = 0; i < 4; ++i) { int idx = base + i; if (idx < N) s += deg[idx]; }
    __shared__ int sm[256];
    sm[tid] = s; __syncthreads();
    for (int d = 128; d > 0; d >>= 1) {
        if (tid < d) sm[tid] += sm[tid + d];
        __syncthreads();
    }
    if (tid == 0) bsum[b] = sm[0];
}
__global__ __launch_bounds__(256) void scan_top(int* __restrict__ bsum,
                                                int* __restrict__ off, int NB, int N) {
    __shared__ int sm[256];
    int tid = threadIdx.x;
    int v = (tid < NB) ? bsum[tid] : 0;
    sm[tid] = v; __syncthreads();
    for (int d = 1; d < 256; d <<= 1) {
        int t = (tid >= d) ? sm[tid - d] : 0;
        __syncthreads();
        sm[tid] += t;
        __syncthreads();
    }
    if (tid < NB) bsum[tid] = sm[tid] - v;
    if (tid == 255) off[N] = sm[255];
}
__global__ __launch_bounds__(256) void scan_fin(const int* __restrict__ deg,
                                                const int* __restrict__ bsum,
                                                int* __restrict__ off, int N) {
    int b = blockIdx.x, tid = threadIdx.x;
    int base = b * 1024 + tid * 4;
    int v[4]; int s = 0;
#pragma unroll
    for (int i = 0; i < 4; ++i) {
        int idx = base + i;
        v[i] = (idx < N) ? deg[idx] : 0;
        s += v[i];
    }
    __shared__ int sm[256];
    sm[tid] = s; __syncthreads();
    for (int d = 1; d < 256; d <<= 1) {
        int t = (tid >= d) ? sm[tid - d] : 0;
        __syncthreads();
        sm[tid] += t;
        __syncthreads();
    }
    int run = bsum[b] + sm[tid] - s;
#pragma unroll
    for (int i = 0; i < 4; ++i) {
        int idx = base + i;
        if (idx < N) { off[idx] = run; run += v[i]; }
    }
}
__global__ void scatter_kernel(const int* __restrict__ src, const int* __restrict__ dst,
                               const int* __restrict__ off, int* __restrict__ cnt,
                               int* __restrict__ csrc, int E)
{
    int i = blockIdx.x * 256 + threadIdx.x;
    if (i < E) {
        int d = dst[i];
        int pos = off[d] + atomicAdd(&cnt[d], 1);
        csrc[pos] = src[i];
    }
}

// ---------------- L2 normalize: one wave per row, f32 -> f32 ------------------------
__global__ __launch_bounds__(256) void nnorm(
    const float* __restrict__ h0, float* __restrict__ emb, int N)
{
    int lane = threadIdx.x & 63, wid = threadIdx.x >> 6;
    int n = blockIdx.x * 4 + wid;
    if (n >= N) return;
    const float2 v = *(const float2*)&h0[(size_t)n * 128 + lane * 2];
    float s = v.x * v.x + v.y * v.y;
#pragma unroll
    for (int m = 1; m < 64; m <<= 1) s += __shfl_xor(s, m);
    float sc = 1.0f / fmaxf(sqrtf(s), 1e-12f);
    if (!isfinite(sc)) sc = 0.f;
    float2* op = (float2*)&emb[(size_t)n * 128 + lane * 2];
    *op = make_float2(v.x * sc, v.y * sc);
}

// ---------------- sentinel (f32) ----------------------------------------------------
__global__ void sentinel_kernel(float* out, int n, float val) {
    int i = blockIdx.x * 256 + threadIdx.x;
    if (i < n) out[i] = val;
}

extern "C" void kernel_launch(void* const* d_in, const int* in_sizes, int n_in,
                              void* d_out, int out_size, void* d_ws, size_t ws_size,
                              hipStream_t stream)
{
    const int N = in_sizes[0] / (TTYPES * INC);
    const int E = in_sizes[19] / 2;
    const size_t NH = (size_t)N * HID;

    // ws: hbuf 2NH f32 | qq N*64 u32 | agg0 NH f32 | kv N*128 u32  (~115 MB)
    const size_t need = 2 * NH * 4 + NH * 2 + NH * 4 + NH * 4;
    if (ws_size < need) {
        sentinel_kernel<<<(out_size + 255) / 256, 256, 0, stream>>>(
            (float*)d_out, out_size, 30.0f);
        return;
    }

    const float* x     = (const float*)d_in[0];
    const float* encW  = (const float*)d_in[1];
    const float* encb  = (const float*)d_in[2];
    const float* kW    = (const float*)d_in[3];
    const float* kb_   = (const float*)d_in[4];
    const float* qW    = (const float*)d_in[5];
    const float* qb    = (const float*)d_in[6];
    const float* vW    = (const float*)d_in[7];
    const float* vb_   = (const float*)d_in[8];
    const float* aW    = (const float*)d_in[9];
    const float* ab    = (const float*)d_in[10];
    const float* skipw = (const float*)d_in[11];
    const float* arel  = (const float*)d_in[12];
    const float* mrel  = (const float*)d_in[13];
    const float* prel  = (const float*)d_in[14];
    const float* dW1   = (const float*)d_in[15];
    const float* db1   = (const float*)d_in[16];
    const float* dW2   = (const float*)d_in[17];
    const float* db2   = (const float*)d_in[18];

    float* hbuf = (float*)d_ws;
    u32* qqb    = (u32*)(hbuf + 2 * NH);         // [N][64] packed bf16 pairs
    float* agg0 = (float*)(qqb + (size_t)N * 64);
    u32* kvbuf  = (u32*)(agg0 + NH);             // [N][128] packed bf16 pairs

    // ---- d_out scratch ----
    float* agg1 = (float*)d_out;                 // emb region, dead before nnorm
    int*   ip   = (int*)((float*)d_out + NH);    // rec region
    int* deg = ip;            ip += N;
    int* cnt = ip;            ip += N;           // adjacent to deg (merged memset)
    int* offs[4];  for (int e = 0; e < 4; ++e) { offs[e] = ip; ip += N + 1; }
    int* csrcs[4]; for (int e = 0; e < 4; ++e) { csrcs[e] = ip; ip += E; }
    float* qWA = (float*)ip;
    float* qbA = qWA + HID * HID;
    int* bsum  = (int*)(qbA + HID);

    static const int st_[4] = {0, 1, 0, 1};
    static const int dt_[4] = {1, 0, 0, 1};
    float* aggs[2] = {agg0, agg1};

    const int egrid = (E + 255) / 256;
    const int RB    = (N + 127) / 128;
    const int GW    = (N + 3) / 4;
    const int NB1   = (N + 1023) >> 10;

    // ---- CSR build (once, reused by both layers) ----
    for (int et = 0; et < 4; ++et) {
        const int* ei = (const int*)d_in[19 + et];
        hipMemsetAsync(deg, 0, (size_t)2 * N * 4, stream);   // deg + cnt
        hist_kernel<<<egrid, 256, 0, stream>>>(ei + E, deg, E);
        scan_part<<<NB1, 256, 0, stream>>>(deg, bsum, N);
        scan_top<<<1, 256, 0, stream>>>(bsum, offs[et], NB1, N);
        scan_fin<<<NB1, 256, 0, stream>>>(deg, bsum, offs[et], N);
        scatter_kernel<<<egrid, 256, 0, stream>>>(ei, ei + E, offs[et], cnt,
                                                  csrcs[et], E);
    }

    // ---- encoder: h[t] = relu(x[t] @ encW[t] + encb[t]) ----
    for (int t = 0; t < TTYPES; ++t) {
        mgemm_kernel<INC, HID, 0, 1, float><<<RB, 256, 0, stream>>>(
            x + (size_t)t * N * INC, encW + (size_t)t * INC * HID, encb + t * HID,
            hbuf + t * NH, N, nullptr, HID);
    }

    for (int l = 0; l < 2; ++l) {
        // group by SOURCE type; st==0 gathers write agg, st==1 accumulate
        for (int st = 0; st < TTYPES; ++st) {
            int bs = l * 2 + st;
            mgemm_kernel<HID, HID, 0, 0, u16><<<RB, 256, 0, stream>>>(
                hbuf + st * NH, kW + (size_t)bs * HID * HID, kb_ + (size_t)bs * HID,
                (u16*)kvbuf, N, nullptr, 256);          // k -> lanes 0-63
            mgemm_kernel<HID, HID, 0, 0, u16><<<RB, 256, 0, stream>>>(
                hbuf + st * NH, vW + (size_t)bs * HID * HID, vb_ + (size_t)bs * HID,
                (u16*)kvbuf + 128, N, nullptr, 256);    // v -> lanes 64-127
            for (int et = 0; et < 4; ++et) {
                if (st_[et] != st) continue;
                int dt = dt_[et];
                int rel = l * 4 + et;
                int bd  = l * 2 + dt;
                fuse_kernel<<<64, 256, 0, stream>>>(
                    qW + (size_t)bd * HID * HID, qb + (size_t)bd * HID,
                    arel + (size_t)rel * 2048, qWA, qbA);
                mgemm_kernel<HID, HID, 0, 0, u16><<<RB, 256, 0, stream>>>(
                    hbuf + dt * NH, qWA, qbA, (u16*)qqb, N, nullptr, HID);
                gather_kernel<<<GW, 256, 0, stream>>>(
                    qqb, kvbuf, offs[et], csrcs[et],
                    prel + (size_t)rel * HH, mrel + (size_t)rel * 2048,
                    aggs[dt], N, st);
            }
        }
        // h[t] = g*(gelu(agg[t]) @ aW + ab) + (1-g)*h[t]
        for (int t = 0; t < TTYPES; ++t) {
            int b = l * 2 + t;
            mgemm_kernel<HID, HID, 1, 2, float><<<RB, 256, 0, stream>>>(
                aggs[t], aW + (size_t)b * HID * HID, ab + (size_t)b * HID,
                hbuf + t * NH, N, skipw + b, HID);
        }
    }

    float* emb = (float*)d_out;           // [N][128] f32
    float* rec = emb + NH;                // [N][256] f32
    nnorm<<<GW, 256, 0, stream>>>(hbuf, emb, N);
    mgemm_kernel<HID, HID, 0, 1, float><<<RB, 256, 0, stream>>>(
        hbuf, dW1, db1, agg0, N, nullptr, HID);
    mgemm_kernel<HID, INC, 0, 0, float><<<RB, 256, 0, stream>>>(
        agg0, dW2, db2, rec, N, nullptr, INC);
}

// Round 18
// 1514.876 us; speedup vs baseline: 1.7959x; 1.1273x over previous
//
#include <hip/hip_runtime.h>
#include <hip/hip_bf16.h>

// HGT forward, MI355X — ROUND 18: gather VALU diet (__expf, 32-bit kv addressing,
// M bank-stagger) + dispatch fusion (SPLIT kv GEMM, paired qq GEMM, gather2 (2 ets),
// CSR build merged to 5 dispatches). All GEMMs MFMA bf16. f32 outputs.

#define HH 8
#define HID 128
#define INC 256
#define TTYPES 2

typedef unsigned short u16;
typedef unsigned int u32;
typedef __attribute__((ext_vector_type(8))) short short8v;
typedef __attribute__((ext_vector_type(4))) float f32x4;

__device__ __forceinline__ float lo2f(u32 u) { return __uint_as_float(u << 16); }
__device__ __forceinline__ float hi2f(u32 u) { return __uint_as_float(u & 0xffff0000u); }
__device__ __forceinline__ u16 f2bf(float f) {
    u32 i = __float_as_uint(f);
    u32 r = i + 0x7fffu + ((i >> 16) & 1u);   // RNE
    return (u16)(r >> 16);
}
__device__ __forceinline__ float gelu_f(float x) {
    return 0.5f * x * (1.0f + erff(x * 0.7071067811865476f));
}

// ---------------- Generalized MFMA GEMM (bf16 frags, f32 accum/epilogue) ------------
// 128 rows/block (2 sub-tiles x 4 waves x 16 rows). W staged per 128x128 chunk to
// LDS transposed [col][k] bf16 stride 136.
// SPLIT: COUT=256 from two separate [128][128] weights W / W2 (k|v fusion).
// AIN: 0 none, 1 gelu. AOUT: 0 none, 1 relu, 2 skip blend (f32 out only).
template <int CIN, int COUT, int AIN, int AOUT, bool SPLIT, typename TOUT>
__global__ __launch_bounds__(256) void mgemm_kernel(
    const float* __restrict__ in, const float* __restrict__ W,
    const float* __restrict__ W2, const float* __restrict__ bias,
    const float* __restrict__ bias2, TOUT* __restrict__ out,
    int nrows, const float* __restrict__ gatep, int ldout)
{
    __shared__ u16 Wt[128 * 136];
    const int tid = threadIdx.x;
    const int lane = tid & 63, wid = tid >> 6;
    const int rsub = lane & 15;
    const int kgrp = (lane >> 4) * 8;
    const int rowblk = blockIdx.x * 128;

    float g = 0.f;
    if (AOUT == 2) g = 1.0f / (1.0f + __expf(-gatep[0]));

#pragma unroll
    for (int cc = 0; cc < COUT; cc += 128) {
        const float* Ws = SPLIT ? (cc ? W2 : W) : W;
        const float* bs = SPLIT ? (cc ? bias2 : bias) : bias;
        const int ldw   = SPLIT ? 128 : COUT;
        const int wcol  = SPLIT ? 0 : cc;

        f32x4 acc[2][8];
#pragma unroll
        for (int t2 = 0; t2 < 2; ++t2)
#pragma unroll
            for (int ct = 0; ct < 8; ++ct) acc[t2][ct] = (f32x4){0.f, 0.f, 0.f, 0.f};

#pragma unroll
        for (int kc = 0; kc < CIN; kc += 128) {
            __syncthreads();
            for (int i = tid; i < 128 * 32; i += 256) {
                int k = i >> 5, c4 = (i & 31) << 2;
                const float4 w =
                    *(const float4*)&Ws[(size_t)(kc + k) * ldw + wcol + c4];
                Wt[(c4 + 0) * 136 + k] = f2bf(w.x);
                Wt[(c4 + 1) * 136 + k] = f2bf(w.y);
                Wt[(c4 + 2) * 136 + k] = f2bf(w.z);
                Wt[(c4 + 3) * 136 + k] = f2bf(w.w);
            }
            __syncthreads();
#pragma unroll
            for (int t2 = 0; t2 < 2; ++t2) {
                const int arow = rowblk + t2 * 64 + wid * 16 + rsub;
                const int asrc = (arow < nrows) ? arow : (nrows - 1);
                const float* ap0 = in + (size_t)asrc * CIN + kc;
#pragma unroll
                for (int ks = 0; ks < 4; ++ks) {
                    const int k0 = ks * 32 + kgrp;
                    const float4 a0 = *(const float4*)(ap0 + k0);
                    const float4 a1 = *(const float4*)(ap0 + k0 + 4);
                    float av[8] = {a0.x, a0.y, a0.z, a0.w, a1.x, a1.y, a1.z, a1.w};
                    short8v a;
#pragma unroll
                    for (int j = 0; j < 8; ++j) {
                        float xv = av[j];
                        if (AIN == 1) xv = gelu_f(xv);
                        a[j] = (short)f2bf(xv);
                    }
#pragma unroll
                    for (int ct = 0; ct < 8; ++ct) {
                        const short8v b =
                            *(const short8v*)&Wt[(ct * 16 + rsub) * 136 + k0];
                        acc[t2][ct] = __builtin_amdgcn_mfma_f32_16x16x32_bf16(
                            a, b, acc[t2][ct], 0, 0, 0);
                    }
                }
            }
        }
#pragma unroll
        for (int t2 = 0; t2 < 2; ++t2) {
            const int orow0 = rowblk + t2 * 64 + wid * 16 + (lane >> 4) * 4;
#pragma unroll
            for (int ct = 0; ct < 8; ++ct) {
                const int col = cc + ct * 16 + rsub;
                const float bv = bs[ct * 16 + rsub + (SPLIT ? 0 : cc)];
#pragma unroll
                for (int r = 0; r < 4; ++r) {
                    const int orow = orow0 + r;
                    if (orow >= nrows) continue;
                    float v = acc[t2][ct][r] + bv;
                    if (AOUT == 1) v = fmaxf(v, 0.f);
                    size_t o = (size_t)orow * ldout + col;
                    if constexpr (sizeof(TOUT) == 2) {
                        ((u16*)out)[o] = f2bf(v);
                    } else {
                        float* of = (float*)out;
                        if (AOUT == 2) v = g * v + (1.0f - g) * of[o];
                        of[o] = v;
                    }
                }
            }
        }
    }
}

// --- fuse arel into qW for TWO edge types (same dt): halves of qWA2 [128][256] ------
__global__ __launch_bounds__(256) void fuse2_kernel(
    const float* __restrict__ qW, const float* __restrict__ qb,
    const float* __restrict__ arelA, const float* __restrict__ arelB,
    float* __restrict__ qWA2, float* __restrict__ qbA2)
{
    const int half = blockIdx.y;
    const float* arel = half ? arelB : arelA;
    __shared__ float Al[2048];
    int tid = threadIdx.x;
    for (int i = tid; i < 2048; i += 256) Al[i] = arel[i];
    __syncthreads();
    int idx = blockIdx.x * 256 + tid;      // 64 x 256 = 16384
    int c = idx >> 7, col = idx & 127;
    int h = col >> 4, d = col & 15;
    const float* Ah = &Al[h * 256 + d * 16];
    const float* qr = &qW[(size_t)c * 128 + h * 16];
    float acc = 0.f;
#pragma unroll
    for (int e = 0; e < 16; ++e) acc += qr[e] * Ah[e];
    qWA2[(size_t)c * 256 + half * 128 + col] = acc;
    if (blockIdx.x == 0 && tid < 128) {
        int h2 = tid >> 4, d2 = tid & 15;
        const float* Ah2 = &Al[h2 * 256 + d2 * 16];
        const float* qb2 = &qb[h2 * 16];
        float accb = 0.f;
#pragma unroll
        for (int e = 0; e < 16; ++e) accb += qb2[e] * Ah2[e];
        qbA2[half * 128 + tid] = accb;
    }
}

// ---------------- CSR-gather attention x2 edge types (blockIdx.y selects) -----------
// kv: [N][128] u32 (k lanes 0-63, v lanes 64-127); qq pre-offset, row stride 128 u32.
__global__ __launch_bounds__(256) void gather2_kernel(
    const u32* __restrict__ qqA, const u32* __restrict__ qqB,
    const u32* __restrict__ kv,
    const int* __restrict__ offA, const int* __restrict__ offB,
    const int* __restrict__ csrcA, const int* __restrict__ csrcB,
    const float* __restrict__ prelA, const float* __restrict__ prelB,
    const float* __restrict__ mrelA, const float* __restrict__ mrelB,
    float* __restrict__ aggA, float* __restrict__ aggB,
    int N, int accA, int accB)
{
    const int which = blockIdx.y;
    const u32* qq   = which ? qqB : qqA;
    const int* off  = which ? offB : offA;
    const int* csrc = which ? csrcB : csrcA;
    const float* prel = which ? prelB : prelA;
    const float* mrel = which ? mrelB : mrelA;
    float* agg = which ? aggB : aggA;
    const int accum = which ? accB : accA;

    __shared__ float M[8 * 264];   // head stride 264: 8-way -> ~2-way bank conflicts
    int tid = threadIdx.x;
    for (int i = tid; i < 2048; i += 256) M[(i >> 8) * 264 + (i & 255)] = mrel[i];
    __syncthreads();
    int lane = tid & 63, wid = tid >> 6;
    int h = lane >> 3, dp = lane & 7;
    int dst = blockIdx.x * 4 + wid;
    if (dst >= N) return;

    float prl = prel[h] * 0.25f;
    const u32 qu = qq[(size_t)dst * 128 + lane];
    const float qx = lo2f(qu), qy = hi2f(qu);
    int beg = off[dst], end = off[dst + 1];
    float acc0 = 0.f, acc1 = 0.f, ssum = 0.f;

    u32 kA[4], vA[4], kB[4], vB[4];

    auto LOADG = [&](int g, u32* kk, u32* vv) {
#pragma unroll
        for (int i = 0; i < 4; ++i) {
            int e = g + i;
            int s = (e < end) ? csrc[e] : 0;
            u32 base = ((u32)s << 7) + lane;
            kk[i] = kv[base];
            vv[i] = kv[base + 64];
        }
    };
    auto COMPG = [&](int g, const u32* kk, const u32* vv) {
#pragma unroll
        for (int i = 0; i < 4; ++i) {
            float p = qx * lo2f(kk[i]) + qy * hi2f(kk[i]);
            p += __shfl_xor(p, 1);
            p += __shfl_xor(p, 2);
            p += __shfl_xor(p, 4);
            float sarg = fminf(fmaxf(p * prl, -60.f), 60.f);
            float ex = (g + i < end) ? __expf(sarg) : 0.f;
            ssum += ex;
            acc0 += ex * lo2f(vv[i]);
            acc1 += ex * hi2f(vv[i]);
        }
    };

    if (beg < end) {
        LOADG(beg, kA, vA);
        int g = beg;
        for (;;) {
            LOADG(g + 4, kB, vB);
            COMPG(g, kA, vA);
            g += 4;
            if (g >= end) break;
            LOADG(g + 4, kA, vA);
            COMPG(g, kB, vB);
            g += 4;
            if (g >= end) break;
        }
    }

    float inv = 1.0f / (ssum + 1e-16f);
    acc0 *= inv; acc1 *= inv;

    float o0 = 0.f, o1 = 0.f;
    const float* Mh = &M[h * 264];
#pragma unroll
    for (int dd = 0; dd < 8; ++dd) {
        float b0 = __shfl(acc0, (h << 3) | dd);
        float b1 = __shfl(acc1, (h << 3) | dd);
        const float2 m0 = *(const float2*)&Mh[(2 * dd) * 16 + dp * 2];
        const float2 m1 = *(const float2*)&Mh[(2 * dd + 1) * 16 + dp * 2];
        o0 += b0 * m0.x + b1 * m1.x;
        o1 += b0 * m0.y + b1 * m1.y;
    }
    float* ap = &agg[(size_t)dst * 128 + lane * 2];
    if (accum) { ap[0] += o0; ap[1] += o1; }
    else       { ap[0] = o0;  ap[1] = o1;  }
}

// ---------------- CSR build (4 edge types per dispatch via blockIdx.y) --------------
__global__ void hist4_kernel(const int* e0, const int* e1, const int* e2,
                             const int* e3, int* __restrict__ deg, int E, int N) {
    int et = blockIdx.y;
    const int* ei = et == 0 ? e0 : et == 1 ? e1 : et == 2 ? e2 : e3;
    int i = blockIdx.x * 256 + threadIdx.x;
    if (i < E) atomicAdd(&deg[et * N + ei[E + i]], 1);
}
__global__ __launch_bounds__(256) void scan_part4(const int* __restrict__ deg,
                                                  int* __restrict__ bsum, int N) {
    int et = blockIdx.y, b = blockIdx.x, tid = threadIdx.x;
    deg += (size_t)et * N;
    int base = b * 1024 + tid * 4;
    int s = 0;
#pragma unroll
    for (int i = 0; i < 4; ++i) { int idx = base + i; if (idx < N) s += deg[idx]; }
    __shared__ int sm[256];
    sm[tid] = s; __syncthreads();
    for (int d = 128; d > 0; d >>= 1) {
        if (tid < d) sm[tid] += sm[tid + d];
        __syncthreads();
    }
    if (tid == 0) bsum[et * 64 + b] = sm[0];
}
__global__ __launch_bounds__(256) void scan_top4(int* __restrict__ bsum,
                                                 int* __restrict__ offs,
                                                 int NB, int N) {
    int et = blockIdx.x, tid = threadIdx.x;
    bsum += et * 64;
    int* off = offs + (size_t)et * (N + 1);
    __shared__ int sm[256];
    int v = (tid < NB) ? bsum[tid] : 0;
    sm[tid] = v; __syncthreads();
    for (int d = 1; d < 256; d <<= 1) {
        int t = (tid >= d) ? sm[tid - d] : 0;
        __syncthreads();
        sm[tid] += t;
        __syncthreads();
    }
    if (tid < NB) bsum[tid] = sm[tid] - v;
    if (tid == 255) off[N] = sm[255];
}
__global__ __launch_bounds__(256) void scan_fin4(const int* __restrict__ deg,
                                                 const int* __restrict__ bsum,
                                                 int* __restrict__ offs, int N) {
    int et = blockIdx.y, b = blockIdx.x, tid = threadIdx.x;
    deg += (size_t)et * N;
    bsum += et * 64;
    int* off = offs + (size_t)et * (N + 1);
    int base = b * 1024 + tid * 4;
    int v[4]; int s = 0;
#pragma unroll
    for (int i = 0; i < 4; ++i) {
        int idx = base + i;
        v[i] = (idx < N) ? deg[idx] : 0;
        s += v[i];
    }
    __shared__ int sm[256];
    sm[tid] = s; __syncthreads();
    for (int d = 1; d < 256; d <<= 1) {
        int t = (tid >= d) ? sm[tid - d] : 0;
        __syncthreads();
        sm[tid] += t;
        __syncthreads();
    }
    int run = bsum[b] + sm[tid] - s;
#pragma unroll
    for (int i = 0; i < 4; ++i) {
        int idx = base + i;
        if (idx < N) { off[idx] = run; run += v[i]; }
    }
}
__global__ void scatter4_kernel(const int* e0, const int* e1, const int* e2,
                                const int* e3, const int* __restrict__ offs,
                                int* __restrict__ cnt, int* __restrict__ csrcs,
                                int E, int N) {
    int et = blockIdx.y;
    const int* ei = et == 0 ? e0 : et == 1 ? e1 : et == 2 ? e2 : e3;
    int i = blockIdx.x * 256 + threadIdx.x;
    if (i < E) {
        int d = ei[E + i];
        int pos = offs[(size_t)et * (N + 1) + d] + atomicAdd(&cnt[et * N + d], 1);
        csrcs[(size_t)et * E + pos] = ei[i];
    }
}

// ---------------- L2 normalize: one wave per row, f32 -> f32 ------------------------
__global__ __launch_bounds__(256) void nnorm(
    const float* __restrict__ h0, float* __restrict__ emb, int N)
{
    int lane = threadIdx.x & 63, wid = threadIdx.x >> 6;
    int n = blockIdx.x * 4 + wid;
    if (n >= N) return;
    const float2 v = *(const float2*)&h0[(size_t)n * 128 + lane * 2];
    float s = v.x * v.x + v.y * v.y;
#pragma unroll
    for (int m = 1; m < 64; m <<= 1) s += __shfl_xor(s, m);
    float sc = 1.0f / fmaxf(sqrtf(s), 1e-12f);
    if (!isfinite(sc)) sc = 0.f;
    float2* op = (float2*)&emb[(size_t)n * 128 + lane * 2];
    *op = make_float2(v.x * sc, v.y * sc);
}

// ---------------- sentinel (f32) ----------------------------------------------------
__global__ void sentinel_kernel(float* out, int n, float val) {
    int i = blockIdx.x * 256 + threadIdx.x;
    if (i < n) out[i] = val;
}

extern "C" void kernel_launch(void* const* d_in, const int* in_sizes, int n_in,
                              void* d_out, int out_size, void* d_ws, size_t ws_size,
                              hipStream_t stream)
{
    const int N = in_sizes[0] / (TTYPES * INC);
    const int E = in_sizes[19] / 2;
    const size_t NH = (size_t)N * HID;

    // ws: hbuf 2NH f32 | agg0 NH f32 | kv NH u32 | qq2_0 NH u32 | qq2_1 NH u32
    const size_t need = 6 * NH * 4;   // 153.6 MB (proven available, r8)
    if (ws_size < need) {
        sentinel_kernel<<<(out_size + 255) / 256, 256, 0, stream>>>(
            (float*)d_out, out_size, 30.0f);
        return;
    }

    const float* x     = (const float*)d_in[0];
    const float* encW  = (const float*)d_in[1];
    const float* encb  = (const float*)d_in[2];
    const float* kW    = (const float*)d_in[3];
    const float* kb_   = (const float*)d_in[4];
    const float* qW    = (const float*)d_in[5];
    const float* qb    = (const float*)d_in[6];
    const float* vW    = (const float*)d_in[7];
    const float* vb_   = (const float*)d_in[8];
    const float* aW    = (const float*)d_in[9];
    const float* ab    = (const float*)d_in[10];
    const float* skipw = (const float*)d_in[11];
    const float* arel  = (const float*)d_in[12];
    const float* mrel  = (const float*)d_in[13];
    const float* prel  = (const float*)d_in[14];
    const float* dW1   = (const float*)d_in[15];
    const float* db1   = (const float*)d_in[16];
    const float* dW2   = (const float*)d_in[17];
    const float* db2   = (const float*)d_in[18];

    float* hbuf = (float*)d_ws;
    float* agg0 = hbuf + 2 * NH;
    u32* kvbuf  = (u32*)(agg0 + NH);             // [N][128] k|v packed bf16
    u32* qq2_0  = kvbuf + NH;                    // [N][128] qq halves, dt=0
    u32* qq2_1  = kvbuf + 2 * NH;                // [N][128] qq halves, dt=1
    u32* qq2[2] = {qq2_0, qq2_1};

    // ---- d_out scratch ----
    float* agg1 = (float*)d_out;                 // emb region, dead before nnorm
    int*   ip   = (int*)((float*)d_out + NH);    // rec region
    int* deg   = ip;  ip += 4 * N;
    int* cnt   = ip;  ip += 4 * N;
    int* offs  = ip;  ip += 4 * (N + 1);
    int* csrcs = ip;  ip += 4 * E;
    float* qWA2 = (float*)ip;
    float* qbA2 = qWA2 + HID * 256;
    int* bsum   = (int*)(qbA2 + 256);            // [4][64]

    static const int dt_[4] = {1, 0, 0, 1};
    float* aggs[2] = {agg0, agg1};

    const int egrid = (E + 255) / 256;
    const int RB    = (N + 127) / 128;
    const int GW    = (N + 3) / 4;
    const int NB1   = (N + 1023) >> 10;

    const int* e0 = (const int*)d_in[19];
    const int* e1 = (const int*)d_in[20];
    const int* e2 = (const int*)d_in[21];
    const int* e3 = (const int*)d_in[22];

    // ---- CSR build: 6 dispatches total for all 4 edge types ----
    hipMemsetAsync(deg, 0, (size_t)8 * N * 4, stream);   // deg + cnt
    hist4_kernel<<<dim3(egrid, 4), 256, 0, stream>>>(e0, e1, e2, e3, deg, E, N);
    scan_part4<<<dim3(NB1, 4), 256, 0, stream>>>(deg, bsum, N);
    scan_top4<<<4, 256, 0, stream>>>(bsum, offs, NB1, N);
    scan_fin4<<<dim3(NB1, 4), 256, 0, stream>>>(deg, bsum, offs, N);
    scatter4_kernel<<<dim3(egrid, 4), 256, 0, stream>>>(e0, e1, e2, e3, offs, cnt,
                                                        csrcs, E, N);

    // ---- encoder ----
    for (int t = 0; t < TTYPES; ++t) {
        mgemm_kernel<INC, HID, 0, 1, false, float><<<RB, 256, 0, stream>>>(
            x + (size_t)t * N * INC, encW + (size_t)t * INC * HID, nullptr,
            encb + t * HID, nullptr, hbuf + t * NH, N, nullptr, HID);
    }

    // dt -> its two edge types (halves of qq2 in this order)
    static const int etdt[2][2] = {{1, 2}, {0, 3}};

    for (int l = 0; l < 2; ++l) {
        // qq2 for both dst types (h pre-update)
        for (int dt = 0; dt < 2; ++dt) {
            int bd = l * 2 + dt;
            fuse2_kernel<<<dim3(64, 2), 256, 0, stream>>>(
                qW + (size_t)bd * HID * HID, qb + (size_t)bd * HID,
                arel + (size_t)(l * 4 + etdt[dt][0]) * 2048,
                arel + (size_t)(l * 4 + etdt[dt][1]) * 2048, qWA2, qbA2);
            mgemm_kernel<HID, 256, 0, 0, false, u16><<<RB, 256, 0, stream>>>(
                hbuf + dt * NH, qWA2, nullptr, qbA2, nullptr,
                (u16*)qq2[dt], N, nullptr, 256);
        }
        // per source type: fused k|v GEMM, then both dependent gathers (one dispatch)
        for (int st = 0; st < TTYPES; ++st) {
            int bs = l * 2 + st;
            mgemm_kernel<HID, 256, 0, 0, true, u16><<<RB, 256, 0, stream>>>(
                hbuf + st * NH, kW + (size_t)bs * HID * HID,
                vW + (size_t)bs * HID * HID, kb_ + (size_t)bs * HID,
                vb_ + (size_t)bs * HID, (u16*)kvbuf, N, nullptr, 256);
            int etA = (st == 0) ? 0 : 1;   // et0/et1 are half0 of their dt pair
            int etB = (st == 0) ? 2 : 3;   // et2/et3 are half1
            const u32* qqA = qq2[dt_[etA]];          // half 0 -> offset 0
            const u32* qqB = qq2[dt_[etB]] + 64;     // half 1 -> offset 64
            int rA = l * 4 + etA, rB = l * 4 + etB;
            gather2_kernel<<<dim3(GW, 2), 256, 0, stream>>>(
                qqA, qqB, kvbuf,
                offs + (size_t)etA * (N + 1), offs + (size_t)etB * (N + 1),
                csrcs + (size_t)etA * E, csrcs + (size_t)etB * E,
                prel + (size_t)rA * HH, prel + (size_t)rB * HH,
                mrel + (size_t)rA * 2048, mrel + (size_t)rB * 2048,
                aggs[dt_[etA]], aggs[dt_[etB]], N, st, st);
        }
        // h[t] = g*(gelu(agg[t]) @ aW + ab) + (1-g)*h[t]
        for (int t = 0; t < TTYPES; ++t) {
            int b = l * 2 + t;
            mgemm_kernel<HID, HID, 1, 2, false, float><<<RB, 256, 0, stream>>>(
                aggs[t], aW + (size_t)b * HID * HID, nullptr, ab + (size_t)b * HID,
                nullptr, hbuf + t * NH, N, skipw + b, HID);
        }
    }

    float* emb = (float*)d_out;           // [N][128] f32
    float* rec = emb + NH;                // [N][256] f32
    nnorm<<<GW, 256, 0, stream>>>(hbuf, emb, N);
    mgemm_kernel<HID, HID, 0, 1, false, float><<<RB, 256, 0, stream>>>(
        hbuf, dW1, nullptr, db1, nullptr, agg0, N, nullptr, HID);
    mgemm_kernel<HID, 256, 0, 0, false, float><<<RB, 256, 0, stream>>>(
        agg0, dW2, nullptr, db2, nullptr, rec, N, nullptr, 256);
}